// Round 2
// baseline (1746.164 us; speedup 1.0000x reference)
//
#include <hip/hip_runtime.h>
#include <hip/hip_bf16.h>
#include <math.h>

typedef __hip_bfloat16 bf16;
typedef __bf16 bf16x8 __attribute__((ext_vector_type(8)));
typedef float f32x4 __attribute__((ext_vector_type(4)));

#define NDEPTH 4
#define DIM 768
#define HEADS 12
#define DH 64
#define INNER 768
#define FFI 2048
#define BB 4
#define NN 1024
#define ROWS (BB*NN)   // 4096

// ---------------------------------------------------------------------------
// bf16 MFMA GEMM: C[MxN] = A[MxK] @ Bt[NxK]^T (+ optional f32 residual Rf).
// A comes from bf16 (Ab) or f32 (Af, converted during staging). Output to
// bf16 (Cb) and/or f32 (Cf). 128x128 tile, BK=32, 4 waves, 4x4 MFMA/wave.
// ---------------------------------------------------------------------------
__global__ __launch_bounds__(256) void gemm_kernel(
    const bf16* __restrict__ Ab, const float* __restrict__ Af,
    const bf16* __restrict__ Bt,
    bf16* __restrict__ Cb, float* __restrict__ Cf, const float* __restrict__ Rf,
    int M, int N, int K)
{
  __shared__ __align__(16) bf16 As[128*32];
  __shared__ __align__(16) bf16 Bs[128*32];
  const int tid  = threadIdx.x;
  const int lane = tid & 63, w = tid >> 6;
  const int quad = lane >> 4, l16 = lane & 15;
  const int wr = w >> 1, wc = w & 1;
  const int m0 = blockIdx.y * 128, n0 = blockIdx.x * 128;

  f32x4 acc[4][4] = {};

  for (int kk = 0; kk < K; kk += 32) {
    __syncthreads();
    for (int c = tid; c < 512; c += 256) {
      int r = c >> 2, j = c & 3;
      if (Af) {
        const float* src = &Af[(size_t)(m0 + r)*K + kk + j*8];
        float4 f0 = *(const float4*)src;
        float4 f1 = *(const float4*)(src + 4);
        union { uint4 u; bf16 h[8]; } p;
        p.h[0] = __float2bfloat16(f0.x); p.h[1] = __float2bfloat16(f0.y);
        p.h[2] = __float2bfloat16(f0.z); p.h[3] = __float2bfloat16(f0.w);
        p.h[4] = __float2bfloat16(f1.x); p.h[5] = __float2bfloat16(f1.y);
        p.h[6] = __float2bfloat16(f1.z); p.h[7] = __float2bfloat16(f1.w);
        *(uint4*)&As[r*32 + j*8] = p.u;
      } else {
        *(uint4*)&As[r*32 + j*8] = *(const uint4*)&Ab[(size_t)(m0 + r)*K + kk + j*8];
      }
      *(uint4*)&Bs[r*32 + j*8] = *(const uint4*)&Bt[(size_t)(n0 + r)*K + kk + j*8];
    }
    __syncthreads();
    bf16x8 af[4], bfr[4];
    #pragma unroll
    for (int mt = 0; mt < 4; ++mt)
      af[mt] = *(const bf16x8*)&As[(wr*64 + mt*16 + l16)*32 + quad*8];
    #pragma unroll
    for (int nt = 0; nt < 4; ++nt)
      bfr[nt] = *(const bf16x8*)&Bs[(wc*64 + nt*16 + l16)*32 + quad*8];
    #pragma unroll
    for (int mt = 0; mt < 4; ++mt)
      #pragma unroll
      for (int nt = 0; nt < 4; ++nt)
        acc[mt][nt] = __builtin_amdgcn_mfma_f32_16x16x32_bf16(af[mt], bfr[nt], acc[mt][nt], 0, 0, 0);
  }

  #pragma unroll
  for (int mt = 0; mt < 4; ++mt) {
    #pragma unroll
    for (int nt = 0; nt < 4; ++nt) {
      int row = m0 + wr*64 + mt*16 + quad*4;
      int col = n0 + wc*64 + nt*16 + l16;
      #pragma unroll
      for (int r = 0; r < 4; ++r) {
        size_t idx = (size_t)(row + r) * N + col;
        float v = acc[mt][nt][r];
        if (Rf) v += Rf[idx];
        if (Cf) Cf[idx] = v;
        if (Cb) Cb[idx] = __float2bfloat16(v);
      }
    }
  }
}

// ---------------------------------------------------------------------------
// LayerNorm (row = 768, f32 in, bf16 out): (x-mu)*rsqrt(var+eps)*g + b
// ---------------------------------------------------------------------------
__global__ __launch_bounds__(256) void ln_kernel(
    const float* __restrict__ x, const float* __restrict__ g,
    const float* __restrict__ bta, bf16* __restrict__ out)
{
  const int row = blockIdx.x, tid = threadIdx.x;
  const size_t base = (size_t)row * DIM;
  float v[3];
  #pragma unroll
  for (int j = 0; j < 3; ++j) v[j] = x[base + tid + j*256];
  float s  = v[0] + v[1] + v[2];
  float ss = v[0]*v[0] + v[1]*v[1] + v[2]*v[2];
  #pragma unroll
  for (int off = 32; off; off >>= 1) { s += __shfl_xor(s, off); ss += __shfl_xor(ss, off); }
  __shared__ float red[8];
  int w = tid >> 6;
  if ((tid & 63) == 0) { red[w] = s; red[w + 4] = ss; }
  __syncthreads();
  s  = red[0] + red[1] + red[2] + red[3];
  ss = red[4] + red[5] + red[6] + red[7];
  float mean = s * (1.f/768.f);
  float var  = ss * (1.f/768.f) - mean*mean;
  float rstd = rsqrtf(fmaxf(var, 0.f) + 1e-5f);
  #pragma unroll
  for (int j = 0; j < 3; ++j) {
    int c = tid + j*256;
    float bv = bta ? bta[c] : 0.f;
    out[base + c] = __float2bfloat16((v[j] - mean) * rstd * g[c] + bv);
  }
}

// ---------------------------------------------------------------------------
// RoPE (2D, H=32) + L2-norm + per-dim scale on q,k; transpose q,k,v to
// (b, h, n, dh). One block per (b,n); one wave per head (3 heads/wave).
// ---------------------------------------------------------------------------
__global__ __launch_bounds__(256) void rope_kernel(
    const bf16* __restrict__ q, const bf16* __restrict__ kv,
    const float* __restrict__ qsc, const float* __restrict__ ksc,
    bf16* __restrict__ qh, bf16* __restrict__ kh, bf16* __restrict__ vh)
{
  const int bn = blockIdx.x;
  const int b = bn >> 10, n = bn & 1023;
  const int tid = threadIdx.x;
  const int w = tid >> 6, d = tid & 63;
  const float xp = (float)(n & 31), yp = (float)(n >> 5);
  const int p = d >> 1, t = p >> 1;
  const float freq = powf(10000.f, -(float)t / 16.f);
  const float ang = (p & 1) ? yp * freq : xp * freq;
  float sn, cs;
  sincosf(ang, &sn, &cs);
  const float qs = qsc[d];
  const float ks = ksc[d];

  for (int hh = w; hh < HEADS; hh += 4) {
    float qv  = __bfloat162float(q [(size_t)bn*INNER     + hh*64 + d]);
    float kv_ = __bfloat162float(kv[(size_t)bn*(2*INNER) + hh*64 + d]);
    float qo = __shfl_xor(qv, 1);
    float ko = __shfl_xor(kv_, 1);
    // even d: r=self, im=partner -> r*c - im*s ; odd d: r=partner, im=self -> r*s + im*c
    float qr = (d & 1) ? (qo*sn + qv*cs) : (qv*cs - qo*sn);
    float kr = (d & 1) ? (ko*sn + kv_*cs) : (kv_*cs - ko*sn);
    float q2 = qr*qr, k2 = kr*kr;
    #pragma unroll
    for (int off = 1; off < 64; off <<= 1) { q2 += __shfl_xor(q2, off); k2 += __shfl_xor(k2, off); }
    float qn = qr / fmaxf(sqrtf(q2), 1e-12f) * qs;
    float kn = kr / fmaxf(sqrtf(k2), 1e-12f) * ks;
    size_t oi = (((size_t)b*HEADS + hh)*NN + n)*DH + d;
    qh[oi] = __float2bfloat16(qn);
    kh[oi] = __float2bfloat16(kn);
    vh[oi] = kv[(size_t)bn*(2*INNER) + INNER + hh*64 + d];
  }
}

// ---------------------------------------------------------------------------
// Flash attention: one block per (qtile=64 rows, b*h). 16 K/V tiles of 64.
// Online softmax, P via padded LDS round-trip, MFMA for QK^T and PV.
// ---------------------------------------------------------------------------
__global__ __launch_bounds__(256) void attn_kernel(
    const bf16* __restrict__ qh, const bf16* __restrict__ kh,
    const bf16* __restrict__ vh, bf16* __restrict__ ob)
{
  __shared__ __align__(16) bf16 Qs[64*72];
  __shared__ __align__(16) bf16 Ks[64*72];
  __shared__ __align__(16) bf16 Vt[64*72];
  __shared__ __align__(16) bf16 Ps[4][16*72];

  const int tid = threadIdx.x;
  const int lane = tid & 63, w = tid >> 6;
  const int quad = lane >> 4, l16 = lane & 15;
  const int qt = blockIdx.x, bh = blockIdx.y;
  const int b = bh / HEADS, h = bh % HEADS;
  const size_t base = (size_t)bh * NN * DH;

  for (int c = tid; c < 512; c += 256) {
    int r = c >> 3, j = c & 7;
    *(uint4*)&Qs[r*72 + j*8] = *(const uint4*)&qh[base + (size_t)(qt*64 + r)*64 + j*8];
  }

  f32x4 o[4] = {};
  float m[4], l[4];
  #pragma unroll
  for (int r = 0; r < 4; ++r) { m[r] = -1e30f; l[r] = 0.f; }

  for (int kt0 = 0; kt0 < NN/64; ++kt0) {
    __syncthreads();
    for (int c = tid; c < 512; c += 256) {
      int r = c >> 3, j = c & 7;
      *(uint4*)&Ks[r*72 + j*8] = *(const uint4*)&kh[base + (size_t)(kt0*64 + r)*64 + j*8];
    }
    {
      int krow = tid & 63, d0 = (tid >> 6) * 16;
      const bf16* vp = &vh[base + (size_t)(kt0*64 + krow)*64 + d0];
      #pragma unroll
      for (int j = 0; j < 16; ++j)
        Vt[(d0 + j)*72 + krow] = vp[j];
    }
    __syncthreads();

    // S = (Q K^T) * 8
    f32x4 s[4] = {};
    bf16x8 aq[2];
    #pragma unroll
    for (int kc = 0; kc < 2; ++kc)
      aq[kc] = *(const bf16x8*)&Qs[(w*16 + l16)*72 + kc*32 + quad*8];
    #pragma unroll
    for (int kt = 0; kt < 4; ++kt)
      #pragma unroll
      for (int kc = 0; kc < 2; ++kc) {
        bf16x8 bk = *(const bf16x8*)&Ks[(kt*16 + l16)*72 + kc*32 + quad*8];
        s[kt] = __builtin_amdgcn_mfma_f32_16x16x32_bf16(aq[kc], bk, s[kt], 0, 0, 0);
      }
    #pragma unroll
    for (int kt = 0; kt < 4; ++kt) s[kt] *= 8.f;

    // online softmax (C layout: row = quad*4+r, col lanes = l16 within quad)
    #pragma unroll
    for (int r = 0; r < 4; ++r) {
      float mx = fmaxf(fmaxf(s[0][r], s[1][r]), fmaxf(s[2][r], s[3][r]));
      #pragma unroll
      for (int off = 1; off < 16; off <<= 1) mx = fmaxf(mx, __shfl_xor(mx, off));
      float mn = fmaxf(m[r], mx);
      float alpha = __expf(m[r] - mn);
      m[r] = mn;
      float rs = 0.f;
      #pragma unroll
      for (int kt = 0; kt < 4; ++kt) {
        float pv = __expf(s[kt][r] - mn);
        s[kt][r] = pv; rs += pv;
      }
      #pragma unroll
      for (int off = 1; off < 16; off <<= 1) rs += __shfl_xor(rs, off);
      l[r] = l[r]*alpha + rs;
      #pragma unroll
      for (int nt = 0; nt < 4; ++nt) o[nt][r] *= alpha;
      #pragma unroll
      for (int kt = 0; kt < 4; ++kt)
        Ps[w][(quad*4 + r)*72 + kt*16 + l16] = __float2bfloat16(s[kt][r]);
    }
    __syncthreads();

    // O += P V
    #pragma unroll
    for (int kc = 0; kc < 2; ++kc) {
      bf16x8 ap = *(const bf16x8*)&Ps[w][l16*72 + kc*32 + quad*8];
      #pragma unroll
      for (int nt = 0; nt < 4; ++nt) {
        bf16x8 bv = *(const bf16x8*)&Vt[(nt*16 + l16)*72 + kc*32 + quad*8];
        o[nt] = __builtin_amdgcn_mfma_f32_16x16x32_bf16(ap, bv, o[nt], 0, 0, 0);
      }
    }
  }

  #pragma unroll
  for (int nt = 0; nt < 4; ++nt)
    #pragma unroll
    for (int r = 0; r < 4; ++r) {
      int n = qt*64 + w*16 + quad*4 + r;
      int dcol = nt*16 + l16;
      ob[((size_t)(b*NN + n)*HEADS + h)*DH + dcol] = __float2bfloat16(o[nt][r] / l[r]);
    }
}

// ---------------------------------------------------------------------------
// SwiGLU: gl[m][j] = u[m][j] * gelu_exact(u[m][2048+j])
// ---------------------------------------------------------------------------
__global__ __launch_bounds__(256) void swiglu_kernel(
    const bf16* __restrict__ u, bf16* __restrict__ gl)
{
  const int row = blockIdx.x, tid = threadIdx.x;
  const size_t ub = (size_t)row * (2*FFI);
  union { uint4 q; bf16 h[8]; } a8, g8, o8;
  a8.q = *(const uint4*)(u + ub + tid*8);
  g8.q = *(const uint4*)(u + ub + FFI + tid*8);
  #pragma unroll
  for (int j = 0; j < 8; ++j) {
    float a = __bfloat162float(a8.h[j]);
    float g = __bfloat162float(g8.h[j]);
    float ge = 0.5f * g * (1.f + erff(g * 0.70710678118654752f));
    o8.h[j] = __float2bfloat16(a * ge);
  }
  *(uint4*)(gl + (size_t)row*FFI + tid*8) = o8.q;
}

// ---------------------------------------------------------------------------
// Transpose f32 (RxC) -> bf16 (CxR), 32x32 LDS tiles
// ---------------------------------------------------------------------------
__global__ __launch_bounds__(256) void transpose_kernel(
    const float* __restrict__ in, bf16* __restrict__ out, int R, int C)
{
  __shared__ float t[32][33];
  const int tx = threadIdx.x & 31, ty = threadIdx.x >> 5;
  const int c0 = blockIdx.x * 32, r0 = blockIdx.y * 32;
  #pragma unroll
  for (int i = 0; i < 4; ++i)
    t[ty + i*8][tx] = in[(size_t)(r0 + ty + i*8)*C + c0 + tx];
  __syncthreads();
  #pragma unroll
  for (int i = 0; i < 4; ++i)
    out[(size_t)(c0 + ty + i*8)*R + r0 + tx] = __float2bfloat16(t[tx][ty + i*8]);
}

// ---------------------------------------------------------------------------
extern "C" void kernel_launch(void* const* d_in, const int* in_sizes, int n_in,
                              void* d_out, int out_size, void* d_ws, size_t ws_size,
                              hipStream_t stream)
{
  const float* x_in       = (const float*)d_in[0];
  const float* attn_gamma = (const float*)d_in[1];
  const float* wq         = (const float*)d_in[2];
  const float* wkv        = (const float*)d_in[3];
  const float* q_scale    = (const float*)d_in[4];
  const float* k_scale    = (const float*)d_in[5];
  const float* wo         = (const float*)d_in[6];
  const float* ff_gamma   = (const float*)d_in[7];
  const float* ff_beta    = (const float*)d_in[8];
  const float* wff1       = (const float*)d_in[9];
  const float* wff2       = (const float*)d_in[10];
  float* outp = (float*)d_out;
  char* ws = (char*)d_ws;

  const size_t E = (size_t)ROWS * DIM;        // 3,145,728 elems
  // Arena (total 24E bytes = 75.5 MB):
  float* xw32 = (float*)ws;                   // [0, 4E)   f32 residual stream
  bf16*  S_h  = (bf16*)(ws + E*4);            // [4E, 6E)  hbuf / obuf / hbuf2
  bf16*  BIG  = (bf16*)(ws + E*6);            // [6E, 22E) 8E bf16 elems
  bf16*  WT   = (bf16*)(ws + E*22);           // [22E,24E) transposed weight slot
  bf16*  qbuf  = BIG;                         // E
  bf16*  kvbuf = BIG + E;                     // 2E
  bf16*  qhb   = BIG + 3*E;                   // E
  bf16*  khb   = BIG + 4*E;                   // E
  bf16*  vhb   = BIG + 5*E;                   // E
  bf16*  ubuf  = BIG;                         // ROWS*4096 = 16,777,216 elems
  bf16*  glbuf = BIG + (size_t)ROWS*2*FFI;    // ROWS*2048 elems (fits 8E exactly)

  for (int i = 0; i < NDEPTH; ++i) {
    const float* xsrc = (i == 0) ? x_in : xw32;

    // h = LN(x) * attn_gamma ; q = h @ wq
    ln_kernel<<<ROWS, 256, 0, stream>>>(xsrc, attn_gamma + i*DIM, nullptr, S_h);
    transpose_kernel<<<dim3(24,24), 256, 0, stream>>>(wq + (size_t)i*589824, WT, 768, 768);
    gemm_kernel<<<dim3(6,32), 256, 0, stream>>>(S_h, nullptr, WT, qbuf, nullptr, nullptr, ROWS, INNER, DIM);
    // kv = x @ wkv  (pre-LN x, f32 path)
    transpose_kernel<<<dim3(48,24), 256, 0, stream>>>(wkv + (size_t)i*1179648, WT, 768, 1536);
    gemm_kernel<<<dim3(12,32), 256, 0, stream>>>(nullptr, xsrc, WT, kvbuf, nullptr, nullptr, ROWS, 2*INNER, DIM);
    // rope + l2norm + scale + head transpose
    rope_kernel<<<ROWS, 256, 0, stream>>>(qbuf, kvbuf, q_scale + i*DH, k_scale + i*DH, qhb, khb, vhb);
    // attention -> obuf (= S_h)
    attn_kernel<<<dim3(16,48), 256, 0, stream>>>(qhb, khb, vhb, S_h);
    // x = x + o @ wo   (f32 residual stream)
    transpose_kernel<<<dim3(24,24), 256, 0, stream>>>(wo + (size_t)i*589824, WT, 768, 768);
    gemm_kernel<<<dim3(6,32), 256, 0, stream>>>(S_h, nullptr, WT, nullptr, xw32, xsrc, ROWS, DIM, INNER);
    // hf = LN(x) * ff_gamma + ff_beta ; u = hf @ wff1
    ln_kernel<<<ROWS, 256, 0, stream>>>(xw32, ff_gamma + i*DIM, ff_beta + i*DIM, S_h);
    transpose_kernel<<<dim3(128,24), 256, 0, stream>>>(wff1 + (size_t)i*3145728, WT, 768, 4096);
    gemm_kernel<<<dim3(32,32), 256, 0, stream>>>(S_h, nullptr, WT, ubuf, nullptr, nullptr, ROWS, 2*FFI, DIM);
    // gl = a * gelu(g) ; x = x + gl @ wff2
    swiglu_kernel<<<ROWS, 256, 0, stream>>>(ubuf, glbuf);
    transpose_kernel<<<dim3(24,64), 256, 0, stream>>>(wff2 + (size_t)i*1572864, WT, 2048, 768);
    if (i < NDEPTH-1)
      gemm_kernel<<<dim3(6,32), 256, 0, stream>>>(glbuf, nullptr, WT, nullptr, xw32, xw32, ROWS, DIM, FFI);
    else
      gemm_kernel<<<dim3(6,32), 256, 0, stream>>>(glbuf, nullptr, WT, nullptr, outp, xw32, ROWS, DIM, FFI);
  }
}

// Round 3
// 1324.350 us; speedup vs baseline: 1.3185x; 1.3185x over previous
//
#include <hip/hip_runtime.h>
#include <hip/hip_bf16.h>
#include <math.h>

typedef __hip_bfloat16 bf16;
typedef __bf16 bf16x8 __attribute__((ext_vector_type(8)));
typedef float f32x4 __attribute__((ext_vector_type(4)));

#define NDEPTH 4
#define DIM 768
#define HEADS 12
#define DH 64
#define INNER 768
#define FFI 2048
#define BB 4
#define NN 1024
#define ROWS (BB*NN)   // 4096

__device__ __forceinline__ void async_cp16(const bf16* g, bf16* l) {
  __builtin_amdgcn_global_load_lds(
      (const __attribute__((address_space(1))) unsigned int*)g,
      (__attribute__((address_space(3))) unsigned int*)l, 16, 0, 0);
}

// ---------------------------------------------------------------------------
// bf16 MFMA GEMM: C[MxN] = A[MxK] @ Bt[NxK]^T (+ optional f32 residual Rf).
// 128xBN tile, BK=32, 4 waves (2x2), global_load_lds width-16 staging (m97).
// GELU=true: N is interleaved (a,g) pairs; epilogue writes a*gelu(g) to Cb
// with N/2 columns (SwiGLU fused, no u materialization).
// ---------------------------------------------------------------------------
template<int BN, bool GELU>
__global__ __launch_bounds__(256) void gemm_kernel(
    const bf16* __restrict__ A, const bf16* __restrict__ Bt,
    bf16* __restrict__ Cb, float* __restrict__ Cf, const float* __restrict__ Rf,
    int M, int N, int K)
{
  constexpr int WN = BN / 2;      // wave col extent
  constexpr int NT = WN / 16;     // col MFMA tiles per wave
  __shared__ __align__(16) bf16 As[128*32];
  __shared__ __align__(16) bf16 Bs[BN*32];
  const int tid  = threadIdx.x;
  const int lane = tid & 63, w = tid >> 6;
  const int quad = lane >> 4, l16 = lane & 15;
  const int wr = w >> 1, wc = w & 1;
  const int m0 = blockIdx.y * 128, n0 = blockIdx.x * BN;

  f32x4 acc[4][NT] = {};

  constexpr int CHA = 512;        // 128 rows x 4 16B-chunks
  constexpr int CHB = BN * 4;
  constexpr int CH  = CHA + CHB;

  for (int kk = 0; kk < K; kk += 32) {
    __syncthreads();
    for (int c0 = w*64; c0 < CH; c0 += 256) {   // c0 wave-uniform (mult of 64)
      int ch = c0 + lane;
      if (c0 < CHA) {
        int r = ch >> 2, j = ch & 3;
        async_cp16(&A[(size_t)(m0 + r)*K + kk + j*8], &As[(size_t)c0*8]);
      } else {
        int ch2 = ch - CHA, r = ch2 >> 2, j = ch2 & 3;
        async_cp16(&Bt[(size_t)(n0 + r)*K + kk + j*8], &Bs[(size_t)(c0 - CHA)*8]);
      }
    }
    __syncthreads();   // drains vmcnt before ds_read

    bf16x8 af[4], bfr[NT];
    #pragma unroll
    for (int mt = 0; mt < 4; ++mt)
      af[mt] = *(const bf16x8*)&As[(wr*64 + mt*16 + l16)*32 + quad*8];
    #pragma unroll
    for (int nt = 0; nt < NT; ++nt)
      bfr[nt] = *(const bf16x8*)&Bs[(wc*WN + nt*16 + l16)*32 + quad*8];
    #pragma unroll
    for (int mt = 0; mt < 4; ++mt)
      #pragma unroll
      for (int nt = 0; nt < NT; ++nt)
        acc[mt][nt] = __builtin_amdgcn_mfma_f32_16x16x32_bf16(af[mt], bfr[nt], acc[mt][nt], 0, 0, 0);
  }

  #pragma unroll
  for (int mt = 0; mt < 4; ++mt) {
    #pragma unroll
    for (int nt = 0; nt < NT; ++nt) {
      int row = m0 + wr*64 + mt*16 + quad*4;
      int col = n0 + wc*WN + nt*16 + l16;
      #pragma unroll
      for (int r = 0; r < 4; ++r) {
        float v = acc[mt][nt][r];
        if (GELU) {
          float g = __shfl_xor(v, 1);            // even lane: v=a, g from odd
          if (!(lane & 1)) {
            float ge = 0.5f * g * (1.f + erff(g * 0.70710678118654752f));
            Cb[(size_t)(row + r)*(N >> 1) + (col >> 1)] = __float2bfloat16(v * ge);
          }
        } else {
          size_t idx = (size_t)(row + r) * N + col;
          if (Rf) v += Rf[idx];
          if (Cf) Cf[idx] = v;
          if (Cb) Cb[idx] = __float2bfloat16(v);
        }
      }
    }
  }
}

// ---------------------------------------------------------------------------
// LayerNorm (row = 768, f32 in, bf16 out)
// ---------------------------------------------------------------------------
__global__ __launch_bounds__(256) void ln_kernel(
    const float* __restrict__ x, const float* __restrict__ g,
    const float* __restrict__ bta, bf16* __restrict__ out)
{
  const int row = blockIdx.x, tid = threadIdx.x;
  const size_t base = (size_t)row * DIM;
  float v[3];
  #pragma unroll
  for (int j = 0; j < 3; ++j) v[j] = x[base + tid + j*256];
  float s  = v[0] + v[1] + v[2];
  float ss = v[0]*v[0] + v[1]*v[1] + v[2]*v[2];
  #pragma unroll
  for (int off = 32; off; off >>= 1) { s += __shfl_xor(s, off); ss += __shfl_xor(ss, off); }
  __shared__ float red[8];
  int w = tid >> 6;
  if ((tid & 63) == 0) { red[w] = s; red[w + 4] = ss; }
  __syncthreads();
  s  = red[0] + red[1] + red[2] + red[3];
  ss = red[4] + red[5] + red[6] + red[7];
  float mean = s * (1.f/768.f);
  float var  = ss * (1.f/768.f) - mean*mean;
  float rstd = rsqrtf(fmaxf(var, 0.f) + 1e-5f);
  #pragma unroll
  for (int j = 0; j < 3; ++j) {
    int c = tid + j*256;
    float bv = bta ? bta[c] : 0.f;
    out[base + c] = __float2bfloat16((v[j] - mean) * rstd * g[c] + bv);
  }
}

// ---------------------------------------------------------------------------
// RoPE (2D, H=32) + L2-norm + per-dim scale on q,k -> (b,h,n,dh)
// ---------------------------------------------------------------------------
__global__ __launch_bounds__(256) void rope_kernel(
    const bf16* __restrict__ q, const bf16* __restrict__ kv,
    const float* __restrict__ qsc, const float* __restrict__ ksc,
    bf16* __restrict__ qh, bf16* __restrict__ kh)
{
  const int bn = blockIdx.x;
  const int b = bn >> 10, n = bn & 1023;
  const int tid = threadIdx.x;
  const int w = tid >> 6, d = tid & 63;
  const float xp = (float)(n & 31), yp = (float)(n >> 5);
  const int p = d >> 1, t = p >> 1;
  const float freq = powf(10000.f, -(float)t / 16.f);
  const float ang = (p & 1) ? yp * freq : xp * freq;
  float sn, cs;
  sincosf(ang, &sn, &cs);
  const float qs = qsc[d];
  const float ks = ksc[d];

  for (int hh = w; hh < HEADS; hh += 4) {
    float qv  = __bfloat162float(q [(size_t)bn*INNER     + hh*64 + d]);
    float kv_ = __bfloat162float(kv[(size_t)bn*(2*INNER) + hh*64 + d]);
    float qo = __shfl_xor(qv, 1);
    float ko = __shfl_xor(kv_, 1);
    float qr = (d & 1) ? (qo*sn + qv*cs) : (qv*cs - qo*sn);
    float kr = (d & 1) ? (ko*sn + kv_*cs) : (kv_*cs - ko*sn);
    float q2 = qr*qr, k2 = kr*kr;
    #pragma unroll
    for (int off = 1; off < 64; off <<= 1) { q2 += __shfl_xor(q2, off); k2 += __shfl_xor(k2, off); }
    float qn = qr / fmaxf(sqrtf(q2), 1e-12f) * qs;
    float kn = kr / fmaxf(sqrtf(k2), 1e-12f) * ks;
    size_t oi = (((size_t)b*HEADS + hh)*NN + n)*DH + d;
    qh[oi] = __float2bfloat16(qn);
    kh[oi] = __float2bfloat16(kn);
  }
}

// ---------------------------------------------------------------------------
// V extract + transpose: kv (b,n,2*INNER) v-part -> vt (b,h,dh,n)
// ---------------------------------------------------------------------------
__global__ __launch_bounds__(256) void vtrans_kernel(
    const bf16* __restrict__ kv, bf16* __restrict__ vt)
{
  __shared__ bf16 t[64][72];
  const int bh = blockIdx.y, n0 = blockIdx.x * 64;
  const int b = bh / HEADS, h = bh % HEADS;
  const int tid = threadIdx.x;
  #pragma unroll
  for (int p = 0; p < 2; ++p) {
    int r = (tid >> 3) + p*32, j = tid & 7;
    *(uint4*)&t[r][j*8] =
      *(const uint4*)&kv[(size_t)(b*NN + n0 + r)*(2*INNER) + INNER + h*64 + j*8];
  }
  __syncthreads();
  #pragma unroll
  for (int p = 0; p < 2; ++p) {
    int d = (tid >> 3) + p*32, j = tid & 7;
    union { uint4 u; bf16 h8[8]; } o;
    #pragma unroll
    for (int e = 0; e < 8; ++e) o.h8[e] = t[j*8 + e][d];
    *(uint4*)&vt[((size_t)bh*DH + d)*NN + n0 + j*8] = o.u;
  }
}

// ---------------------------------------------------------------------------
// Flash attention: block = (64 q-rows, b*h); 16 K/V tiles of 64; V pre-
// transposed in global (b,h,dh,n). Online softmax; P via padded LDS.
// ---------------------------------------------------------------------------
__global__ __launch_bounds__(256) void attn_kernel(
    const bf16* __restrict__ qh, const bf16* __restrict__ kh,
    const bf16* __restrict__ vt, bf16* __restrict__ ob)
{
  __shared__ __align__(16) bf16 Qs[64*72];
  __shared__ __align__(16) bf16 Ks[64*72];
  __shared__ __align__(16) bf16 Vt[64*72];
  __shared__ __align__(16) bf16 Ps[4][16*72];

  const int tid = threadIdx.x;
  const int lane = tid & 63, w = tid >> 6;
  const int quad = lane >> 4, l16 = lane & 15;
  const int qt = blockIdx.x, bh = blockIdx.y;
  const int b = bh / HEADS, h = bh % HEADS;
  const size_t base = (size_t)bh * NN * DH;

  for (int c = tid; c < 512; c += 256) {
    int r = c >> 3, j = c & 7;
    *(uint4*)&Qs[r*72 + j*8] = *(const uint4*)&qh[base + (size_t)(qt*64 + r)*64 + j*8];
  }

  f32x4 o[4] = {};
  float m[4], l[4];
  #pragma unroll
  for (int r = 0; r < 4; ++r) { m[r] = -1e30f; l[r] = 0.f; }

  for (int kt0 = 0; kt0 < NN/64; ++kt0) {
    __syncthreads();
    for (int c = tid; c < 512; c += 256) {
      int r = c >> 3, j = c & 7;
      *(uint4*)&Ks[r*72 + j*8] = *(const uint4*)&kh[base + (size_t)(kt0*64 + r)*64 + j*8];
      *(uint4*)&Vt[r*72 + j*8] = *(const uint4*)&vt[base + (size_t)r*NN + kt0*64 + j*8];
    }
    __syncthreads();

    // S = (Q K^T) * 8
    f32x4 s[4] = {};
    bf16x8 aq[2];
    #pragma unroll
    for (int kc = 0; kc < 2; ++kc)
      aq[kc] = *(const bf16x8*)&Qs[(w*16 + l16)*72 + kc*32 + quad*8];
    #pragma unroll
    for (int kt = 0; kt < 4; ++kt)
      #pragma unroll
      for (int kc = 0; kc < 2; ++kc) {
        bf16x8 bk = *(const bf16x8*)&Ks[(kt*16 + l16)*72 + kc*32 + quad*8];
        s[kt] = __builtin_amdgcn_mfma_f32_16x16x32_bf16(aq[kc], bk, s[kt], 0, 0, 0);
      }
    #pragma unroll
    for (int kt = 0; kt < 4; ++kt) s[kt] *= 8.f;

    // online softmax (C layout: row = quad*4+r, cols = l16 groups)
    #pragma unroll
    for (int r = 0; r < 4; ++r) {
      float mx = fmaxf(fmaxf(s[0][r], s[1][r]), fmaxf(s[2][r], s[3][r]));
      #pragma unroll
      for (int off = 1; off < 16; off <<= 1) mx = fmaxf(mx, __shfl_xor(mx, off));
      float mn = fmaxf(m[r], mx);
      float alpha = __expf(m[r] - mn);
      m[r] = mn;
      float rs = 0.f;
      #pragma unroll
      for (int kt = 0; kt < 4; ++kt) {
        float pv = __expf(s[kt][r] - mn);
        s[kt][r] = pv; rs += pv;
      }
      #pragma unroll
      for (int off = 1; off < 16; off <<= 1) rs += __shfl_xor(rs, off);
      l[r] = l[r]*alpha + rs;
      #pragma unroll
      for (int nt = 0; nt < 4; ++nt) o[nt][r] *= alpha;
      #pragma unroll
      for (int kt = 0; kt < 4; ++kt)
        Ps[w][(quad*4 + r)*72 + kt*16 + l16] = __float2bfloat16(s[kt][r]);
    }
    __syncthreads();

    // O += P V
    #pragma unroll
    for (int kc = 0; kc < 2; ++kc) {
      bf16x8 ap = *(const bf16x8*)&Ps[w][l16*72 + kc*32 + quad*8];
      #pragma unroll
      for (int nt = 0; nt < 4; ++nt) {
        bf16x8 bv = *(const bf16x8*)&Vt[(nt*16 + l16)*72 + kc*32 + quad*8];
        o[nt] = __builtin_amdgcn_mfma_f32_16x16x32_bf16(ap, bv, o[nt], 0, 0, 0);
      }
    }
  }

  #pragma unroll
  for (int nt = 0; nt < 4; ++nt)
    #pragma unroll
    for (int r = 0; r < 4; ++r) {
      int n = qt*64 + w*16 + quad*4 + r;
      int dcol = nt*16 + l16;
      ob[((size_t)(b*NN + n)*HEADS + h)*DH + dcol] = __float2bfloat16(o[nt][r] / l[r]);
    }
}

// ---------------------------------------------------------------------------
// f32 -> bf16 cast (vectorized x8)
// ---------------------------------------------------------------------------
__global__ __launch_bounds__(256) void cast_kernel(
    const float* __restrict__ x, bf16* __restrict__ o)
{
  size_t i = ((size_t)blockIdx.x*256 + threadIdx.x) * 8;
  float4 f0 = *(const float4*)(x + i);
  float4 f1 = *(const float4*)(x + i + 4);
  union { uint4 u; bf16 h[8]; } p;
  p.h[0] = __float2bfloat16(f0.x); p.h[1] = __float2bfloat16(f0.y);
  p.h[2] = __float2bfloat16(f0.z); p.h[3] = __float2bfloat16(f0.w);
  p.h[4] = __float2bfloat16(f1.x); p.h[5] = __float2bfloat16(f1.y);
  p.h[6] = __float2bfloat16(f1.z); p.h[7] = __float2bfloat16(f1.w);
  *(uint4*)(o + i) = p.u;
}

// ---------------------------------------------------------------------------
// Fused weight transpose: 5 weights f32 (RxC) -> bf16 (CxR), one dispatch.
// perm=1 (wff1): output rows interleave a/g columns: rout = 2c | 2(c-half)+1
// ---------------------------------------------------------------------------
struct TD { const float* src; bf16* dst; int R, C, base, perm; };
struct TDs5 { TD d[5]; };

__global__ __launch_bounds__(256) void wtrans_kernel(TDs5 a)
{
  const int blk = blockIdx.x;
  int di = 0;
  #pragma unroll
  for (int k = 1; k < 5; ++k) if (blk >= a.d[k].base) di = k;
  const TD d = a.d[di];
  const int local = blk - d.base;
  const int tilesX = d.C >> 5;
  const int by = local / tilesX, bx = local - by*tilesX;
  __shared__ float t[32][33];
  const int tx = threadIdx.x & 31, ty = threadIdx.x >> 5;
  const int c0 = bx*32, r0 = by*32;
  #pragma unroll
  for (int i = 0; i < 4; ++i)
    t[ty + i*8][tx] = d.src[(size_t)(r0 + ty + i*8)*d.C + c0 + tx];
  __syncthreads();
  const int half = d.C >> 1;
  #pragma unroll
  for (int i = 0; i < 4; ++i) {
    int c = c0 + ty + i*8;
    int rout = d.perm ? ((c < half) ? 2*c : 2*(c - half) + 1) : c;
    d.dst[(size_t)rout*d.R + r0 + tx] = __float2bfloat16(t[tx][ty + i*8]);
  }
}

// ---------------------------------------------------------------------------
extern "C" void kernel_launch(void* const* d_in, const int* in_sizes, int n_in,
                              void* d_out, int out_size, void* d_ws, size_t ws_size,
                              hipStream_t stream)
{
  const float* x_in       = (const float*)d_in[0];
  const float* attn_gamma = (const float*)d_in[1];
  const float* wq         = (const float*)d_in[2];
  const float* wkv        = (const float*)d_in[3];
  const float* q_scale    = (const float*)d_in[4];
  const float* k_scale    = (const float*)d_in[5];
  const float* wo         = (const float*)d_in[6];
  const float* ff_gamma   = (const float*)d_in[7];
  const float* ff_beta    = (const float*)d_in[8];
  const float* wff1       = (const float*)d_in[9];
  const float* wff2       = (const float*)d_in[10];
  float* outp = (float*)d_out;
  char* ws = (char*)d_ws;

  const size_t E = (size_t)ROWS * DIM;      // 3,145,728 elems
  // Arena (bytes): xw32 4E | xw16 2E | S_h 2E | BIG 12E | WT 4.5E  = 24.5E
  float* xw32 = (float*)ws;                     // f32 residual stream
  bf16*  xw16 = (bf16*)(ws + E*4);              // bf16 residual shadow (kv input)
  bf16*  S_h  = (bf16*)(ws + E*6);              // LN out / attn out
  bf16*  BIG  = (bf16*)(ws + E*8);              // 6E elems
  bf16*  WT   = (bf16*)(ws + E*20);             // 7,077,888 elems transposed wts
  bf16*  qbuf  = BIG;                           // E
  bf16*  kvbuf = BIG + E;                       // 2E
  bf16*  qhb   = BIG + 3*E;                     // E
  bf16*  khb   = BIG + 4*E;                     // E
  bf16*  vtb   = BIG + 5*E;                     // E
  bf16*  glbuf = BIG;                           // ROWS*FFI (overlays q..vt, dead)
  bf16*  wqT   = WT;                            // [768][768]
  bf16*  wkvT  = WT + 589824;                   // [1536][768]
  bf16*  woT   = WT + 1769472;                  // [768][768]
  bf16*  wff1T = WT + 2359296;                  // [4096][768] (interleaved a/g)
  bf16*  wff2T = WT + 5505024;                  // [768][2048]

  cast_kernel<<<1536, 256, 0, stream>>>(x_in, xw16);

  for (int i = 0; i < NDEPTH; ++i) {
    const float* xsrc = (i == 0) ? x_in : xw32;

    TDs5 td;
    td.d[0] = { wq   + (size_t)i*589824,  wqT,   768,  768,    0, 0 };
    td.d[1] = { wkv  + (size_t)i*1179648, wkvT,  768, 1536,  576, 0 };
    td.d[2] = { wo   + (size_t)i*589824,  woT,   768,  768, 1728, 0 };
    td.d[3] = { wff1 + (size_t)i*3145728, wff1T, 768, 4096, 2304, 1 };
    td.d[4] = { wff2 + (size_t)i*1572864, wff2T, 2048, 768, 5376, 0 };
    wtrans_kernel<<<6912, 256, 0, stream>>>(td);

    // h = LN(x)*attn_gamma ; q = h @ wq ; kv = x @ wkv (bf16 shadow input)
    ln_kernel<<<ROWS, 256, 0, stream>>>(xsrc, attn_gamma + i*DIM, nullptr, S_h);
    gemm_kernel<64,false><<<dim3(12,32), 256, 0, stream>>>(S_h,  wqT,  qbuf,  nullptr, nullptr, ROWS, INNER,   DIM);
    gemm_kernel<128,false><<<dim3(12,32), 256, 0, stream>>>(xw16, wkvT, kvbuf, nullptr, nullptr, ROWS, 2*INNER, DIM);
    // rope(q,k) + l2norm + scale ; v -> (b,h,dh,n)
    rope_kernel<<<ROWS, 256, 0, stream>>>(qbuf, kvbuf, q_scale + i*DH, k_scale + i*DH, qhb, khb);
    vtrans_kernel<<<dim3(16,48), 256, 0, stream>>>(kvbuf, vtb);
    attn_kernel<<<dim3(16,48), 256, 0, stream>>>(qhb, khb, vtb, S_h);
    // x = x + o @ wo  (f32 residual)
    gemm_kernel<64,false><<<dim3(12,32), 256, 0, stream>>>(S_h, woT, nullptr, xw32, xsrc, ROWS, DIM, INNER);
    // hf = LN(x)*ff_gamma + ff_beta ; gl = a*gelu(g) fused in FF1 epilogue
    ln_kernel<<<ROWS, 256, 0, stream>>>(xw32, ff_gamma + i*DIM, ff_beta + i*DIM, S_h);
    gemm_kernel<128,true><<<dim3(32,32), 256, 0, stream>>>(S_h, wff1T, glbuf, nullptr, nullptr, ROWS, 2*FFI, DIM);
    // x = x + gl @ wff2  (+ bf16 shadow for next layer's kv)
    if (i < NDEPTH-1)
      gemm_kernel<64,false><<<dim3(12,32), 256, 0, stream>>>(glbuf, wff2T, xw16, xw32, xw32, ROWS, DIM, FFI);
    else
      gemm_kernel<64,false><<<dim3(12,32), 256, 0, stream>>>(glbuf, wff2T, nullptr, outp, xw32, ROWS, DIM, FFI);
  }
}

// Round 4
// 1174.366 us; speedup vs baseline: 1.4869x; 1.1277x over previous
//
#include <hip/hip_runtime.h>
#include <hip/hip_bf16.h>
#include <math.h>

typedef __hip_bfloat16 bf16;
typedef __bf16 bf16x8 __attribute__((ext_vector_type(8)));
typedef float f32x4 __attribute__((ext_vector_type(4)));

#define NDEPTH 4
#define DIM 768
#define HEADS 12
#define DH 64
#define INNER 768
#define FFI 2048
#define BB 4
#define NN 1024
#define ROWS (BB*NN)   // 4096

__device__ __forceinline__ void async_cp16(const bf16* g, bf16* l) {
  __builtin_amdgcn_global_load_lds(
      (const __attribute__((address_space(1))) unsigned int*)g,
      (__attribute__((address_space(3))) unsigned int*)l, 16, 0, 0);
}

// ---------------------------------------------------------------------------
// bf16 MFMA GEMM body: C[MxN] = A[MxK] @ Bt[NxK]^T (+ optional f32 residual).
// 128xBN tile, BK=64, 4 waves (2x2), global_load_lds width-16 staging.
// LDS XOR-swizzle: chunk (row r, j) holds global chunk j^(r&7) -> conflict-
// free ds_read_b128 (2-way = free). All ds_read addrs are K-loop invariant.
// GELU=true: N is interleaved (a,g); epilogue writes a*gelu(g), N/2 cols.
// ---------------------------------------------------------------------------
template<int BN, bool GELU>
__device__ __forceinline__ void gemm_body(
    const bf16* __restrict__ A, const bf16* __restrict__ Bt,
    bf16* __restrict__ Cb, float* __restrict__ Cf, const float* __restrict__ Rf,
    int M, int N, int K, int bx, int by, bf16* As, bf16* Bs)
{
  constexpr int WN = BN / 2;      // wave col extent
  constexpr int NT = WN / 16;     // col MFMA tiles per wave
  const int tid  = threadIdx.x;
  const int lane = tid & 63, w = tid >> 6;
  const int quad = lane >> 4, l16 = lane & 15;
  const int wr = w >> 1, wc = w & 1;
  const int m0 = by * 128, n0 = bx * BN;

  f32x4 acc[4][NT] = {};

  constexpr int CHA = 128 * 8;    // A chunks (8 x 16B per 64-elem row)
  constexpr int CH  = CHA + BN * 8;

  for (int kk = 0; kk < K; kk += 64) {
    __syncthreads();
    for (int c0 = w*64; c0 < CH; c0 += 256) {   // c0 wave-uniform
      int ch = c0 + lane;
      if (c0 < CHA) {
        int r = ch >> 3, j = (ch & 7) ^ (r & 7);
        async_cp16(&A[(size_t)(m0 + r)*K + kk + j*8], &As[(size_t)c0*8]);
      } else {
        int ch2 = ch - CHA, r = ch2 >> 3, j = (ch2 & 7) ^ (r & 7);
        async_cp16(&Bt[(size_t)(n0 + r)*K + kk + j*8], &Bs[(size_t)(c0 - CHA)*8]);
      }
    }
    __syncthreads();   // drains vmcnt before ds_read

    #pragma unroll
    for (int kc = 0; kc < 2; ++kc) {
      bf16x8 bfr[NT];
      #pragma unroll
      for (int nt = 0; nt < NT; ++nt) {
        int rb = wc*WN + nt*16 + l16;
        int c  = (kc*4 + quad) ^ (rb & 7);
        bfr[nt] = *(const bf16x8*)&Bs[rb*64 + c*8];
      }
      #pragma unroll
      for (int mt = 0; mt < 4; ++mt) {
        int ra = wr*64 + mt*16 + l16;
        int ca = (kc*4 + quad) ^ (ra & 7);
        bf16x8 af = *(const bf16x8*)&As[ra*64 + ca*8];
        #pragma unroll
        for (int nt = 0; nt < NT; ++nt)
          acc[mt][nt] = __builtin_amdgcn_mfma_f32_16x16x32_bf16(af, bfr[nt], acc[mt][nt], 0, 0, 0);
      }
    }
  }

  #pragma unroll
  for (int mt = 0; mt < 4; ++mt) {
    #pragma unroll
    for (int nt = 0; nt < NT; ++nt) {
      int row = m0 + wr*64 + mt*16 + quad*4;
      int col = n0 + wc*WN + nt*16 + l16;
      #pragma unroll
      for (int r = 0; r < 4; ++r) {
        float v = acc[mt][nt][r];
        if (GELU) {
          float g = __shfl_xor(v, 1);            // even lane: v=a, g from odd
          if (!(lane & 1)) {
            float ge = 0.5f * g * (1.f + erff(g * 0.70710678118654752f));
            Cb[(size_t)(row + r)*(N >> 1) + (col >> 1)] = __float2bfloat16(v * ge);
          }
        } else {
          size_t idx = (size_t)(row + r) * N + col;
          if (Rf) v += Rf[idx];
          if (Cf) Cf[idx] = v;
          if (Cb) Cb[idx] = __float2bfloat16(v);
        }
      }
    }
  }
}

template<int BN, bool GELU>
__global__ __launch_bounds__(256) void gemm_kernel(
    const bf16* __restrict__ A, const bf16* __restrict__ Bt,
    bf16* __restrict__ Cb, float* __restrict__ Cf, const float* __restrict__ Rf,
    int M, int N, int K)
{
  __shared__ __align__(16) bf16 As[128*64];
  __shared__ __align__(16) bf16 Bs[BN*64];
  gemm_body<BN,GELU>(A, Bt, Cb, Cf, Rf, M, N, K, blockIdx.x, blockIdx.y, As, Bs);
}

// q = h @ wq (BN=64) and kv = x @ wkv (BN=128) in one dispatch (z-partition)
__global__ __launch_bounds__(256) void qkv_kernel(
    const bf16* __restrict__ h, const bf16* __restrict__ x16,
    const bf16* __restrict__ wqT, const bf16* __restrict__ wkvT,
    bf16* __restrict__ qb, bf16* __restrict__ kvb)
{
  __shared__ __align__(16) bf16 As[128*64];
  __shared__ __align__(16) bf16 Bs[128*64];
  if (blockIdx.z == 0)
    gemm_body<64,false>(h, wqT, qb, nullptr, nullptr, ROWS, INNER, DIM,
                        blockIdx.x, blockIdx.y, As, Bs);
  else
    gemm_body<128,false>(x16, wkvT, kvb, nullptr, nullptr, ROWS, 2*INNER, DIM,
                         blockIdx.x, blockIdx.y, As, Bs);
}

// ---------------------------------------------------------------------------
// LayerNorm (row = 768, f32 in, bf16 out)
// ---------------------------------------------------------------------------
__global__ __launch_bounds__(256) void ln_kernel(
    const float* __restrict__ x, const float* __restrict__ g,
    const float* __restrict__ bta, bf16* __restrict__ out)
{
  const int row = blockIdx.x, tid = threadIdx.x;
  const size_t base = (size_t)row * DIM;
  float v[3];
  #pragma unroll
  for (int j = 0; j < 3; ++j) v[j] = x[base + tid + j*256];
  float s  = v[0] + v[1] + v[2];
  float ss = v[0]*v[0] + v[1]*v[1] + v[2]*v[2];
  #pragma unroll
  for (int off = 32; off; off >>= 1) { s += __shfl_xor(s, off); ss += __shfl_xor(ss, off); }
  __shared__ float red[8];
  int w = tid >> 6;
  if ((tid & 63) == 0) { red[w] = s; red[w + 4] = ss; }
  __syncthreads();
  s  = red[0] + red[1] + red[2] + red[3];
  ss = red[4] + red[5] + red[6] + red[7];
  float mean = s * (1.f/768.f);
  float var  = ss * (1.f/768.f) - mean*mean;
  float rstd = rsqrtf(fmaxf(var, 0.f) + 1e-5f);
  #pragma unroll
  for (int j = 0; j < 3; ++j) {
    int c = tid + j*256;
    float bv = bta ? bta[c] : 0.f;
    out[base + c] = __float2bfloat16((v[j] - mean) * rstd * g[c] + bv);
  }
}

// ---------------------------------------------------------------------------
// RoPE (2D, H=32) + L2-norm + per-dim scale on q,k -> (b,h,n,dh)
// ---------------------------------------------------------------------------
__global__ __launch_bounds__(256) void rope_kernel(
    const bf16* __restrict__ q, const bf16* __restrict__ kv,
    const float* __restrict__ qsc, const float* __restrict__ ksc,
    bf16* __restrict__ qh, bf16* __restrict__ kh)
{
  const int bn = blockIdx.x;
  const int b = bn >> 10, n = bn & 1023;
  const int tid = threadIdx.x;
  const int w = tid >> 6, d = tid & 63;
  const float xp = (float)(n & 31), yp = (float)(n >> 5);
  const int p = d >> 1, t = p >> 1;
  const float freq = powf(10000.f, -(float)t / 16.f);
  const float ang = (p & 1) ? yp * freq : xp * freq;
  float sn, cs;
  sincosf(ang, &sn, &cs);
  const float qs = qsc[d];
  const float ks = ksc[d];

  for (int hh = w; hh < HEADS; hh += 4) {
    float qv  = __bfloat162float(q [(size_t)bn*INNER     + hh*64 + d]);
    float kv_ = __bfloat162float(kv[(size_t)bn*(2*INNER) + hh*64 + d]);
    float qo = __shfl_xor(qv, 1);
    float ko = __shfl_xor(kv_, 1);
    float qr = (d & 1) ? (qo*sn + qv*cs) : (qv*cs - qo*sn);
    float kr = (d & 1) ? (ko*sn + kv_*cs) : (kv_*cs - ko*sn);
    float q2 = qr*qr, k2 = kr*kr;
    #pragma unroll
    for (int off = 1; off < 64; off <<= 1) { q2 += __shfl_xor(q2, off); k2 += __shfl_xor(k2, off); }
    float qn = qr / fmaxf(sqrtf(q2), 1e-12f) * qs;
    float kn = kr / fmaxf(sqrtf(k2), 1e-12f) * ks;
    size_t oi = (((size_t)b*HEADS + hh)*NN + n)*DH + d;
    qh[oi] = __float2bfloat16(qn);
    kh[oi] = __float2bfloat16(kn);
  }
}

// ---------------------------------------------------------------------------
// V extract + transpose: kv (b,n,2*INNER) v-part -> vt (b,h,dh,n)
// ---------------------------------------------------------------------------
__global__ __launch_bounds__(256) void vtrans_kernel(
    const bf16* __restrict__ kv, bf16* __restrict__ vt)
{
  __shared__ bf16 t[64][72];
  const int bh = blockIdx.y, n0 = blockIdx.x * 64;
  const int b = bh / HEADS, h = bh % HEADS;
  const int tid = threadIdx.x;
  #pragma unroll
  for (int p = 0; p < 2; ++p) {
    int r = (tid >> 3) + p*32, j = tid & 7;
    *(uint4*)&t[r][j*8] =
      *(const uint4*)&kv[(size_t)(b*NN + n0 + r)*(2*INNER) + INNER + h*64 + j*8];
  }
  __syncthreads();
  #pragma unroll
  for (int p = 0; p < 2; ++p) {
    int d = (tid >> 3) + p*32, j = tid & 7;
    union { uint4 u; bf16 h8[8]; } o;
    #pragma unroll
    for (int e = 0; e < 8; ++e) o.h8[e] = t[j*8 + e][d];
    *(uint4*)&vt[((size_t)bh*DH + d)*NN + n0 + j*8] = o.u;
  }
}

// ---------------------------------------------------------------------------
// Flash attention: block = (64 q-rows, b*h); 16 K/V tiles of 64; V pre-
// transposed in global (b,h,dh,n). Online softmax; P via padded LDS.
// ---------------------------------------------------------------------------
__global__ __launch_bounds__(256) void attn_kernel(
    const bf16* __restrict__ qh, const bf16* __restrict__ kh,
    const bf16* __restrict__ vt, bf16* __restrict__ ob)
{
  __shared__ __align__(16) bf16 Qs[64*72];
  __shared__ __align__(16) bf16 Ks[64*72];
  __shared__ __align__(16) bf16 Vt[64*72];
  __shared__ __align__(16) bf16 Ps[4][16*72];

  const int tid = threadIdx.x;
  const int lane = tid & 63, w = tid >> 6;
  const int quad = lane >> 4, l16 = lane & 15;
  const int qt = blockIdx.x, bh = blockIdx.y;
  const int b = bh / HEADS, h = bh % HEADS;
  const size_t base = (size_t)bh * NN * DH;

  for (int c = tid; c < 512; c += 256) {
    int r = c >> 3, j = c & 7;
    *(uint4*)&Qs[r*72 + j*8] = *(const uint4*)&qh[base + (size_t)(qt*64 + r)*64 + j*8];
  }

  f32x4 o[4] = {};
  float m[4], l[4];
  #pragma unroll
  for (int r = 0; r < 4; ++r) { m[r] = -1e30f; l[r] = 0.f; }

  for (int kt0 = 0; kt0 < NN/64; ++kt0) {
    __syncthreads();
    for (int c = tid; c < 512; c += 256) {
      int r = c >> 3, j = c & 7;
      *(uint4*)&Ks[r*72 + j*8] = *(const uint4*)&kh[base + (size_t)(kt0*64 + r)*64 + j*8];
      *(uint4*)&Vt[r*72 + j*8] = *(const uint4*)&vt[base + (size_t)r*NN + kt0*64 + j*8];
    }
    __syncthreads();

    // S = (Q K^T) * 8
    f32x4 s[4] = {};
    bf16x8 aq[2];
    #pragma unroll
    for (int kc = 0; kc < 2; ++kc)
      aq[kc] = *(const bf16x8*)&Qs[(w*16 + l16)*72 + kc*32 + quad*8];
    #pragma unroll
    for (int kt = 0; kt < 4; ++kt)
      #pragma unroll
      for (int kc = 0; kc < 2; ++kc) {
        bf16x8 bk = *(const bf16x8*)&Ks[(kt*16 + l16)*72 + kc*32 + quad*8];
        s[kt] = __builtin_amdgcn_mfma_f32_16x16x32_bf16(aq[kc], bk, s[kt], 0, 0, 0);
      }
    #pragma unroll
    for (int kt = 0; kt < 4; ++kt) s[kt] *= 8.f;

    // online softmax (C layout: row = quad*4+r, cols = l16 groups)
    #pragma unroll
    for (int r = 0; r < 4; ++r) {
      float mx = fmaxf(fmaxf(s[0][r], s[1][r]), fmaxf(s[2][r], s[3][r]));
      #pragma unroll
      for (int off = 1; off < 16; off <<= 1) mx = fmaxf(mx, __shfl_xor(mx, off));
      float mn = fmaxf(m[r], mx);
      float alpha = __expf(m[r] - mn);
      m[r] = mn;
      float rs = 0.f;
      #pragma unroll
      for (int kt = 0; kt < 4; ++kt) {
        float pv = __expf(s[kt][r] - mn);
        s[kt][r] = pv; rs += pv;
      }
      #pragma unroll
      for (int off = 1; off < 16; off <<= 1) rs += __shfl_xor(rs, off);
      l[r] = l[r]*alpha + rs;
      #pragma unroll
      for (int nt = 0; nt < 4; ++nt) o[nt][r] *= alpha;
      #pragma unroll
      for (int kt = 0; kt < 4; ++kt)
        Ps[w][(quad*4 + r)*72 + kt*16 + l16] = __float2bfloat16(s[kt][r]);
    }
    __syncthreads();

    // O += P V
    #pragma unroll
    for (int kc = 0; kc < 2; ++kc) {
      bf16x8 ap = *(const bf16x8*)&Ps[w][l16*72 + kc*32 + quad*8];
      #pragma unroll
      for (int nt = 0; nt < 4; ++nt) {
        bf16x8 bv = *(const bf16x8*)&Vt[(nt*16 + l16)*72 + kc*32 + quad*8];
        o[nt] = __builtin_amdgcn_mfma_f32_16x16x32_bf16(ap, bv, o[nt], 0, 0, 0);
      }
    }
  }

  #pragma unroll
  for (int nt = 0; nt < 4; ++nt)
    #pragma unroll
    for (int r = 0; r < 4; ++r) {
      int n = qt*64 + w*16 + quad*4 + r;
      int dcol = nt*16 + l16;
      ob[((size_t)(b*NN + n)*HEADS + h)*DH + dcol] = __float2bfloat16(o[nt][r] / l[r]);
    }
}

// ---------------------------------------------------------------------------
// f32 -> bf16 cast (vectorized x8)
// ---------------------------------------------------------------------------
__global__ __launch_bounds__(256) void cast_kernel(
    const float* __restrict__ x, bf16* __restrict__ o)
{
  size_t i = ((size_t)blockIdx.x*256 + threadIdx.x) * 8;
  float4 f0 = *(const float4*)(x + i);
  float4 f1 = *(const float4*)(x + i + 4);
  union { uint4 u; bf16 h[8]; } p;
  p.h[0] = __float2bfloat16(f0.x); p.h[1] = __float2bfloat16(f0.y);
  p.h[2] = __float2bfloat16(f0.z); p.h[3] = __float2bfloat16(f0.w);
  p.h[4] = __float2bfloat16(f1.x); p.h[5] = __float2bfloat16(f1.y);
  p.h[6] = __float2bfloat16(f1.z); p.h[7] = __float2bfloat16(f1.w);
  *(uint4*)(o + i) = p.u;
}

// ---------------------------------------------------------------------------
// Fused weight transpose: 5 weights f32 (RxC) -> bf16 (CxR), one dispatch.
// perm=1 (wff1): output rows interleave a/g columns: rout = 2c | 2(c-half)+1
// ---------------------------------------------------------------------------
struct TD { const float* src; bf16* dst; int R, C, base, perm; };
struct TDs5 { TD d[5]; };

__global__ __launch_bounds__(256) void wtrans_kernel(TDs5 a)
{
  const int blk = blockIdx.x;
  int di = 0;
  #pragma unroll
  for (int k = 1; k < 5; ++k) if (blk >= a.d[k].base) di = k;
  const TD d = a.d[di];
  const int local = blk - d.base;
  const int tilesX = d.C >> 5;
  const int by = local / tilesX, bx = local - by*tilesX;
  __shared__ float t[32][33];
  const int tx = threadIdx.x & 31, ty = threadIdx.x >> 5;
  const int c0 = bx*32, r0 = by*32;
  #pragma unroll
  for (int i = 0; i < 4; ++i)
    t[ty + i*8][tx] = d.src[(size_t)(r0 + ty + i*8)*d.C + c0 + tx];
  __syncthreads();
  const int half = d.C >> 1;
  #pragma unroll
  for (int i = 0; i < 4; ++i) {
    int c = c0 + ty + i*8;
    int rout = d.perm ? ((c < half) ? 2*c : 2*(c - half) + 1) : c;
    d.dst[(size_t)rout*d.R + r0 + tx] = __float2bfloat16(t[tx][ty + i*8]);
  }
}

// ---------------------------------------------------------------------------
extern "C" void kernel_launch(void* const* d_in, const int* in_sizes, int n_in,
                              void* d_out, int out_size, void* d_ws, size_t ws_size,
                              hipStream_t stream)
{
  const float* x_in       = (const float*)d_in[0];
  const float* attn_gamma = (const float*)d_in[1];
  const float* wq         = (const float*)d_in[2];
  const float* wkv        = (const float*)d_in[3];
  const float* q_scale    = (const float*)d_in[4];
  const float* k_scale    = (const float*)d_in[5];
  const float* wo         = (const float*)d_in[6];
  const float* ff_gamma   = (const float*)d_in[7];
  const float* ff_beta    = (const float*)d_in[8];
  const float* wff1       = (const float*)d_in[9];
  const float* wff2       = (const float*)d_in[10];
  float* outp = (float*)d_out;
  char* ws = (char*)d_ws;

  const size_t E = (size_t)ROWS * DIM;      // 3,145,728 elems
  float* xw32 = (float*)ws;                     // f32 residual stream
  bf16*  xw16 = (bf16*)(ws + E*4);              // bf16 residual shadow (kv input)
  bf16*  S_h  = (bf16*)(ws + E*6);              // LN out / attn out
  bf16*  BIG  = (bf16*)(ws + E*8);              // 6E elems
  bf16*  WT   = (bf16*)(ws + E*20);             // transposed weights
  bf16*  qbuf  = BIG;                           // E
  bf16*  kvbuf = BIG + E;                       // 2E
  bf16*  qhb   = BIG + 3*E;                     // E
  bf16*  khb   = BIG + 4*E;                     // E
  bf16*  vtb   = BIG + 5*E;                     // E
  bf16*  glbuf = BIG;                           // ROWS*FFI (overlays q..vt, dead)
  bf16*  wqT   = WT;                            // [768][768]
  bf16*  wkvT  = WT + 589824;                   // [1536][768]
  bf16*  woT   = WT + 1769472;                  // [768][768]
  bf16*  wff1T = WT + 2359296;                  // [4096][768] (interleaved a/g)
  bf16*  wff2T = WT + 5505024;                  // [768][2048]

  cast_kernel<<<1536, 256, 0, stream>>>(x_in, xw16);

  for (int i = 0; i < NDEPTH; ++i) {
    const float* xsrc = (i == 0) ? x_in : xw32;

    TDs5 td;
    td.d[0] = { wq   + (size_t)i*589824,  wqT,   768,  768,    0, 0 };
    td.d[1] = { wkv  + (size_t)i*1179648, wkvT,  768, 1536,  576, 0 };
    td.d[2] = { wo   + (size_t)i*589824,  woT,   768,  768, 1728, 0 };
    td.d[3] = { wff1 + (size_t)i*3145728, wff1T, 768, 4096, 2304, 1 };
    td.d[4] = { wff2 + (size_t)i*1572864, wff2T, 2048, 768, 5376, 0 };
    wtrans_kernel<<<6912, 256, 0, stream>>>(td);

    // h = LN(x)*attn_gamma ; q = h @ wq ; kv = x @ wkv  (one dispatch)
    ln_kernel<<<ROWS, 256, 0, stream>>>(xsrc, attn_gamma + i*DIM, nullptr, S_h);
    qkv_kernel<<<dim3(12,32,2), 256, 0, stream>>>(S_h, xw16, wqT, wkvT, qbuf, kvbuf);
    // rope(q,k) + l2norm + scale ; v -> (b,h,dh,n)
    rope_kernel<<<ROWS, 256, 0, stream>>>(qbuf, kvbuf, q_scale + i*DH, k_scale + i*DH, qhb, khb);
    vtrans_kernel<<<dim3(16,48), 256, 0, stream>>>(kvbuf, vtb);
    attn_kernel<<<dim3(16,48), 256, 0, stream>>>(qhb, khb, vtb, S_h);
    // x = x + o @ wo  (f32 residual)
    gemm_kernel<64,false><<<dim3(12,32), 256, 0, stream>>>(S_h, woT, nullptr, xw32, xsrc, ROWS, DIM, INNER);
    // hf = LN(x)*ff_gamma + ff_beta ; gl = a*gelu(g) fused in FF1 epilogue
    ln_kernel<<<ROWS, 256, 0, stream>>>(xw32, ff_gamma + i*DIM, ff_beta + i*DIM, S_h);
    gemm_kernel<128,true><<<dim3(32,32), 256, 0, stream>>>(S_h, wff1T, glbuf, nullptr, nullptr, ROWS, 2*FFI, DIM);
    // x = x + gl @ wff2  (+ bf16 shadow for next layer's kv)
    if (i < NDEPTH-1)
      gemm_kernel<64,false><<<dim3(12,32), 256, 0, stream>>>(glbuf, wff2T, xw16, xw32, xw32, ROWS, DIM, FFI);
    else
      gemm_kernel<64,false><<<dim3(12,32), 256, 0, stream>>>(glbuf, wff2T, nullptr, outp, xw32, ROWS, DIM, FFI);
  }
}

// Round 5
// 1010.984 us; speedup vs baseline: 1.7272x; 1.1616x over previous
//
#include <hip/hip_runtime.h>
#include <hip/hip_bf16.h>
#include <math.h>

typedef __hip_bfloat16 bf16;
typedef __bf16 bf16x8 __attribute__((ext_vector_type(8)));
typedef float f32x4 __attribute__((ext_vector_type(4)));

#define NDEPTH 4
#define DIM 768
#define HEADS 12
#define DH 64
#define INNER 768
#define FFI 2048
#define BB 4
#define NN 1024
#define ROWS (BB*NN)   // 4096

__device__ __forceinline__ void async_cp16(const bf16* g, bf16* l) {
  __builtin_amdgcn_global_load_lds(
      (const __attribute__((address_space(1))) unsigned int*)g,
      (__attribute__((address_space(3))) unsigned int*)l, 16, 0, 0);
}

// ---------------------------------------------------------------------------
// bf16 MFMA GEMM body: C[MxN] = A[MxK] @ Bt[NxK]^T (+ optional f32 residual).
// 128xBN tile, BK=64, 4 waves (2x2), global_load_lds width-16 staging.
// LDS XOR-swizzle: chunk (row r, j) holds global chunk j^(r&7) -> conflict-
// free ds_read_b128. K = loop length, LD = row stride (split-K uses LD > K).
// GELU=true: N interleaved (a,g); epilogue writes a*gelu(g), N/2 cols.
// ---------------------------------------------------------------------------
template<int BN, bool GELU>
__device__ __forceinline__ void gemm_body(
    const bf16* __restrict__ A, const bf16* __restrict__ Bt,
    bf16* __restrict__ Cb, float* __restrict__ Cf, const float* __restrict__ Rf,
    int M, int N, int K, int LD, int bx, int by, bf16* As, bf16* Bs)
{
  constexpr int WN = BN / 2;      // wave col extent
  constexpr int NT = WN / 16;     // col MFMA tiles per wave
  const int tid  = threadIdx.x;
  const int lane = tid & 63, w = tid >> 6;
  const int quad = lane >> 4, l16 = lane & 15;
  const int wr = w >> 1, wc = w & 1;
  const int m0 = by * 128, n0 = bx * BN;

  f32x4 acc[4][NT] = {};

  constexpr int CHA = 128 * 8;    // A chunks (8 x 16B per 64-elem row)
  constexpr int CH  = CHA + BN * 8;

  for (int kk = 0; kk < K; kk += 64) {
    __syncthreads();
    for (int c0 = w*64; c0 < CH; c0 += 256) {   // c0 wave-uniform
      int ch = c0 + lane;
      if (c0 < CHA) {
        int r = ch >> 3, j = (ch & 7) ^ (r & 7);
        async_cp16(&A[(size_t)(m0 + r)*LD + kk + j*8], &As[(size_t)c0*8]);
      } else {
        int ch2 = ch - CHA, r = ch2 >> 3, j = (ch2 & 7) ^ (r & 7);
        async_cp16(&Bt[(size_t)(n0 + r)*LD + kk + j*8], &Bs[(size_t)(c0 - CHA)*8]);
      }
    }
    __syncthreads();   // drains vmcnt before ds_read

    #pragma unroll
    for (int kc = 0; kc < 2; ++kc) {
      bf16x8 bfr[NT];
      #pragma unroll
      for (int nt = 0; nt < NT; ++nt) {
        int rb = wc*WN + nt*16 + l16;
        int c  = (kc*4 + quad) ^ (rb & 7);
        bfr[nt] = *(const bf16x8*)&Bs[rb*64 + c*8];
      }
      #pragma unroll
      for (int mt = 0; mt < 4; ++mt) {
        int ra = wr*64 + mt*16 + l16;
        int ca = (kc*4 + quad) ^ (ra & 7);
        bf16x8 af = *(const bf16x8*)&As[ra*64 + ca*8];
        #pragma unroll
        for (int nt = 0; nt < NT; ++nt)
          acc[mt][nt] = __builtin_amdgcn_mfma_f32_16x16x32_bf16(af, bfr[nt], acc[mt][nt], 0, 0, 0);
      }
    }
  }

  #pragma unroll
  for (int mt = 0; mt < 4; ++mt) {
    #pragma unroll
    for (int nt = 0; nt < NT; ++nt) {
      int row = m0 + wr*64 + mt*16 + quad*4;
      int col = n0 + wc*WN + nt*16 + l16;
      #pragma unroll
      for (int r = 0; r < 4; ++r) {
        float v = acc[mt][nt][r];
        if (GELU) {
          float g = __shfl_xor(v, 1);            // even lane: v=a, g from odd
          if (!(lane & 1)) {
            float ge = 0.5f * g * (1.f + erff(g * 0.70710678118654752f));
            Cb[(size_t)(row + r)*(N >> 1) + (col >> 1)] = __float2bfloat16(v * ge);
          }
        } else {
          size_t idx = (size_t)(row + r) * N + col;
          if (Rf) v += Rf[idx];
          if (Cf) Cf[idx] = v;
          if (Cb) Cb[idx] = __float2bfloat16(v);
        }
      }
    }
  }
}

template<int BN, bool GELU>
__global__ __launch_bounds__(256) void gemm_kernel(
    const bf16* __restrict__ A, const bf16* __restrict__ Bt,
    bf16* __restrict__ Cb, float* __restrict__ Cf, const float* __restrict__ Rf,
    int M, int N, int K)
{
  __shared__ __align__(16) bf16 As[128*64];
  __shared__ __align__(16) bf16 Bs[BN*64];
  gemm_body<BN,GELU>(A, Bt, Cb, Cf, Rf, M, N, K, K, blockIdx.x, blockIdx.y, As, Bs);
}

// Split-K=2: z selects K-half; partials to P[z*M*N]
template<int BN>
__global__ __launch_bounds__(256) void gemm_splitk_kernel(
    const bf16* __restrict__ A, const bf16* __restrict__ Bt,
    float* __restrict__ P, int M, int N, int K)
{
  __shared__ __align__(16) bf16 As[128*64];
  __shared__ __align__(16) bf16 Bs[BN*64];
  const int z = blockIdx.z, KH = K >> 1;
  gemm_body<BN,false>(A + (size_t)z*KH, Bt + (size_t)z*KH, nullptr,
                      P + (size_t)z*M*N, nullptr,
                      M, N, KH, K, blockIdx.x, blockIdx.y, As, Bs);
}

// q = h @ wq (BN=64) and kv = x @ wkv (BN=128) in one dispatch (z-partition)
__global__ __launch_bounds__(256) void qkv_kernel(
    const bf16* __restrict__ h, const bf16* __restrict__ x16,
    const bf16* __restrict__ wqT, const bf16* __restrict__ wkvT,
    bf16* __restrict__ qb, bf16* __restrict__ kvb)
{
  __shared__ __align__(16) bf16 As[128*64];
  __shared__ __align__(16) bf16 Bs[128*64];
  if (blockIdx.z == 0)
    gemm_body<64,false>(h, wqT, qb, nullptr, nullptr, ROWS, INNER, DIM, DIM,
                        blockIdx.x, blockIdx.y, As, Bs);
  else
    gemm_body<128,false>(x16, wkvT, kvb, nullptr, nullptr, ROWS, 2*INNER, DIM, DIM,
                         blockIdx.x, blockIdx.y, As, Bs);
}

// ---------------------------------------------------------------------------
// LayerNorm (row = 768, f32 in, bf16 out) — used once for layer-0 attn-LN
// ---------------------------------------------------------------------------
__global__ __launch_bounds__(256) void ln_kernel(
    const float* __restrict__ x, const float* __restrict__ g,
    const float* __restrict__ bta, bf16* __restrict__ out)
{
  const int row = blockIdx.x, tid = threadIdx.x;
  const size_t base = (size_t)row * DIM;
  float v[3];
  #pragma unroll
  for (int j = 0; j < 3; ++j) v[j] = x[base + tid + j*256];
  float s  = v[0] + v[1] + v[2];
  float ss = v[0]*v[0] + v[1]*v[1] + v[2]*v[2];
  #pragma unroll
  for (int off = 32; off; off >>= 1) { s += __shfl_xor(s, off); ss += __shfl_xor(ss, off); }
  __shared__ float red[8];
  int w = tid >> 6;
  if ((tid & 63) == 0) { red[w] = s; red[w + 4] = ss; }
  __syncthreads();
  s  = red[0] + red[1] + red[2] + red[3];
  ss = red[4] + red[5] + red[6] + red[7];
  float mean = s * (1.f/768.f);
  float var  = ss * (1.f/768.f) - mean*mean;
  float rstd = rsqrtf(fmaxf(var, 0.f) + 1e-5f);
  #pragma unroll
  for (int j = 0; j < 3; ++j) {
    int c = tid + j*256;
    float bv = bta ? bta[c] : 0.f;
    out[base + c] = __float2bfloat16((v[j] - mean) * rstd * g[c] + bv);
  }
}

// ---------------------------------------------------------------------------
// Split-K reduce + residual + optional LN (fused). Row = 768.
// x = res + P0 + P1; optionally write x (f32 / bf16 / out f32); if g given,
// also LN(x)*g + beta -> lnout.
// ---------------------------------------------------------------------------
__global__ __launch_bounds__(256) void redln_kernel(
    const float* __restrict__ P0, const float* __restrict__ P1,
    const float* __restrict__ res,
    float* __restrict__ xo32, bf16* __restrict__ xo16, float* __restrict__ outf,
    const float* __restrict__ g, const float* __restrict__ bta,
    bf16* __restrict__ lnout)
{
  const int row = blockIdx.x, tid = threadIdx.x;
  const size_t base = (size_t)row * DIM;
  float v[3];
  #pragma unroll
  for (int j = 0; j < 3; ++j) {
    size_t idx = base + tid + j*256;
    v[j] = res[idx] + P0[idx] + P1[idx];
    if (xo32) xo32[idx] = v[j];
    if (xo16) xo16[idx] = __float2bfloat16(v[j]);
    if (outf) outf[idx] = v[j];
  }
  if (!g) return;
  float s  = v[0] + v[1] + v[2];
  float ss = v[0]*v[0] + v[1]*v[1] + v[2]*v[2];
  #pragma unroll
  for (int off = 32; off; off >>= 1) { s += __shfl_xor(s, off); ss += __shfl_xor(ss, off); }
  __shared__ float red[8];
  int w = tid >> 6;
  if ((tid & 63) == 0) { red[w] = s; red[w + 4] = ss; }
  __syncthreads();
  s  = red[0] + red[1] + red[2] + red[3];
  ss = red[4] + red[5] + red[6] + red[7];
  float mean = s * (1.f/768.f);
  float var  = ss * (1.f/768.f) - mean*mean;
  float rstd = rsqrtf(fmaxf(var, 0.f) + 1e-5f);
  #pragma unroll
  for (int j = 0; j < 3; ++j) {
    int c = tid + j*256;
    float bv = bta ? bta[c] : 0.f;
    lnout[base + c] = __float2bfloat16((v[j] - mean) * rstd * g[c] + bv);
  }
}

// ---------------------------------------------------------------------------
// RoPE (2D, H=32) + L2-norm + per-dim scale; q gets ATTN_SCALE folded in.
// Pair-per-lane: both rotation elements in-lane (no shfl for rotation).
// Block = 384 threads: 12 heads x 32 pairs. -> (b,h,n,dh)
// ---------------------------------------------------------------------------
__global__ __launch_bounds__(384) void rope_kernel(
    const bf16* __restrict__ q, const bf16* __restrict__ kv,
    const float* __restrict__ qsc, const float* __restrict__ ksc,
    bf16* __restrict__ qh, bf16* __restrict__ kh)
{
  const int bn = blockIdx.x;
  const int b = bn >> 10, n = bn & 1023;
  const int tid = threadIdx.x;
  const int h = tid >> 5, pr = tid & 31, d0 = pr*2;
  const float xp = (float)(n & 31), yp = (float)(n >> 5);
  const int t = pr >> 1;
  const float freq = powf(10000.f, -(float)t / 16.f);
  const float ang = (pr & 1) ? yp * freq : xp * freq;
  float sn, cs;
  sincosf(ang, &sn, &cs);
  const float2 qs2 = *(const float2*)&qsc[d0];
  const float2 ks2 = *(const float2*)&ksc[d0];

  union { unsigned int u; bf16 h2[2]; } qa, ka, qo, ko;
  qa.u = *(const unsigned int*)&q [(size_t)bn*INNER      + h*64 + d0];
  ka.u = *(const unsigned int*)&kv[(size_t)bn*(2*INNER)  + h*64 + d0];
  float qre = __bfloat162float(qa.h2[0]), qim = __bfloat162float(qa.h2[1]);
  float kre = __bfloat162float(ka.h2[0]), kim = __bfloat162float(ka.h2[1]);
  float qr = qre*cs - qim*sn, qi = qre*sn + qim*cs;
  float kr = kre*cs - kim*sn, ki = kre*sn + kim*cs;
  float q2 = qr*qr + qi*qi, k2 = kr*kr + ki*ki;
  #pragma unroll
  for (int off = 1; off < 32; off <<= 1) { q2 += __shfl_xor(q2, off); k2 += __shfl_xor(k2, off); }
  float qinv = 8.f / fmaxf(sqrtf(q2), 1e-12f);   // ATTN_SCALE folded into q
  float kinv = 1.f / fmaxf(sqrtf(k2), 1e-12f);
  qo.h2[0] = __float2bfloat16(qr * qinv * qs2.x);
  qo.h2[1] = __float2bfloat16(qi * qinv * qs2.y);
  ko.h2[0] = __float2bfloat16(kr * kinv * ks2.x);
  ko.h2[1] = __float2bfloat16(ki * kinv * ks2.y);
  size_t oi = (((size_t)b*HEADS + h)*NN + n)*DH + d0;
  *(unsigned int*)&qh[oi] = qo.u;
  *(unsigned int*)&kh[oi] = ko.u;
}

// ---------------------------------------------------------------------------
// V extract + transpose: kv (b,n,2*INNER) v-part -> vt (b,h,dh,n)
// ---------------------------------------------------------------------------
__global__ __launch_bounds__(256) void vtrans_kernel(
    const bf16* __restrict__ kv, bf16* __restrict__ vt)
{
  __shared__ bf16 t[64][72];
  const int bh = blockIdx.y, n0 = blockIdx.x * 64;
  const int b = bh / HEADS, h = bh % HEADS;
  const int tid = threadIdx.x;
  #pragma unroll
  for (int p = 0; p < 2; ++p) {
    int r = (tid >> 3) + p*32, j = tid & 7;
    *(uint4*)&t[r][j*8] =
      *(const uint4*)&kv[(size_t)(b*NN + n0 + r)*(2*INNER) + INNER + h*64 + j*8];
  }
  __syncthreads();
  #pragma unroll
  for (int p = 0; p < 2; ++p) {
    int d = (tid >> 3) + p*32, j = tid & 7;
    union { uint4 u; bf16 h8[8]; } o;
    #pragma unroll
    for (int e = 0; e < 8; ++e) o.h8[e] = t[j*8 + e][d];
    *(uint4*)&vt[((size_t)bh*DH + d)*NN + n0 + j*8] = o.u;
  }
}

// ---------------------------------------------------------------------------
// Flash attention with FIXED softmax max: sim <= 8*max|qs|*max|ks| (Cauchy-
// Schwarz on l2-normed q,k; the 8 is folded into qh). No running max, no
// alpha rescale; per-lane l partials reduced once at the end.
// ---------------------------------------------------------------------------
__global__ __launch_bounds__(256) void attn_kernel(
    const bf16* __restrict__ qh, const bf16* __restrict__ kh,
    const bf16* __restrict__ vt, const float* __restrict__ qsc,
    const float* __restrict__ ksc, bf16* __restrict__ ob)
{
  __shared__ __align__(16) bf16 Qs[64*72];
  __shared__ __align__(16) bf16 Ks[64*72];
  __shared__ __align__(16) bf16 Vt[64*72];
  __shared__ __align__(16) bf16 Ps[4][16*72];

  const int tid = threadIdx.x;
  const int lane = tid & 63, w = tid >> 6;
  const int quad = lane >> 4, l16 = lane & 15;
  const int qt = blockIdx.x, bh = blockIdx.y;
  const int b = bh / HEADS, h = bh % HEADS;
  const size_t base = (size_t)bh * NN * DH;

  // static softmax bound: M = 8 * max|qs| * max|ks| (8 folded into qh)
  float mq = fabsf(qsc[lane]), mk = fabsf(ksc[lane]);
  #pragma unroll
  for (int off = 1; off < 64; off <<= 1) {
    mq = fmaxf(mq, __shfl_xor(mq, off));
    mk = fmaxf(mk, __shfl_xor(mk, off));
  }
  const float Mb = 8.f * mq * mk;

  for (int c = tid; c < 512; c += 256) {
    int r = c >> 3, j = c & 7;
    *(uint4*)&Qs[r*72 + j*8] = *(const uint4*)&qh[base + (size_t)(qt*64 + r)*64 + j*8];
  }

  f32x4 o[4] = {};
  float pl[4] = {0.f, 0.f, 0.f, 0.f};

  for (int kt0 = 0; kt0 < NN/64; ++kt0) {
    __syncthreads();
    for (int c = tid; c < 512; c += 256) {
      int r = c >> 3, j = c & 7;
      *(uint4*)&Ks[r*72 + j*8] = *(const uint4*)&kh[base + (size_t)(kt0*64 + r)*64 + j*8];
      *(uint4*)&Vt[r*72 + j*8] = *(const uint4*)&vt[base + (size_t)r*NN + kt0*64 + j*8];
    }
    __syncthreads();

    // S = Q K^T  (scale folded into Q)
    f32x4 s[4] = {};
    bf16x8 aq[2];
    #pragma unroll
    for (int kc = 0; kc < 2; ++kc)
      aq[kc] = *(const bf16x8*)&Qs[(w*16 + l16)*72 + kc*32 + quad*8];
    #pragma unroll
    for (int kt = 0; kt < 4; ++kt)
      #pragma unroll
      for (int kc = 0; kc < 2; ++kc) {
        bf16x8 bk = *(const bf16x8*)&Ks[(kt*16 + l16)*72 + kc*32 + quad*8];
        s[kt] = __builtin_amdgcn_mfma_f32_16x16x32_bf16(aq[kc], bk, s[kt], 0, 0, 0);
      }

    // p = exp(s - Mb); accumulate per-lane denominators
    #pragma unroll
    for (int r = 0; r < 4; ++r) {
      #pragma unroll
      for (int kt = 0; kt < 4; ++kt) {
        float pv = __expf(s[kt][r] - Mb);
        pl[r] += pv;
        Ps[w][(quad*4 + r)*72 + kt*16 + l16] = __float2bfloat16(pv);
      }
    }
    __syncthreads();

    // O += P V
    #pragma unroll
    for (int kc = 0; kc < 2; ++kc) {
      bf16x8 ap = *(const bf16x8*)&Ps[w][l16*72 + kc*32 + quad*8];
      #pragma unroll
      for (int nt = 0; nt < 4; ++nt) {
        bf16x8 bv = *(const bf16x8*)&Vt[(nt*16 + l16)*72 + kc*32 + quad*8];
        o[nt] = __builtin_amdgcn_mfma_f32_16x16x32_bf16(ap, bv, o[nt], 0, 0, 0);
      }
    }
  }

  // reduce l across the 16 column-lanes of each quad
  float l[4];
  #pragma unroll
  for (int r = 0; r < 4; ++r) {
    float rs = pl[r];
    #pragma unroll
    for (int off = 1; off < 16; off <<= 1) rs += __shfl_xor(rs, off);
    l[r] = rs;
  }

  #pragma unroll
  for (int nt = 0; nt < 4; ++nt)
    #pragma unroll
    for (int r = 0; r < 4; ++r) {
      int n = qt*64 + w*16 + quad*4 + r;
      int dcol = nt*16 + l16;
      ob[((size_t)(b*NN + n)*HEADS + h)*DH + dcol] = __float2bfloat16(o[nt][r] / l[r]);
    }
}

// ---------------------------------------------------------------------------
// f32 -> bf16 cast (vectorized x8)
// ---------------------------------------------------------------------------
__global__ __launch_bounds__(256) void cast_kernel(
    const float* __restrict__ x, bf16* __restrict__ o)
{
  size_t i = ((size_t)blockIdx.x*256 + threadIdx.x) * 8;
  float4 f0 = *(const float4*)(x + i);
  float4 f1 = *(const float4*)(x + i + 4);
  union { uint4 u; bf16 h[8]; } p;
  p.h[0] = __float2bfloat16(f0.x); p.h[1] = __float2bfloat16(f0.y);
  p.h[2] = __float2bfloat16(f0.z); p.h[3] = __float2bfloat16(f0.w);
  p.h[4] = __float2bfloat16(f1.x); p.h[5] = __float2bfloat16(f1.y);
  p.h[6] = __float2bfloat16(f1.z); p.h[7] = __float2bfloat16(f1.w);
  *(uint4*)(o + i) = p.u;
}

// ---------------------------------------------------------------------------
// Fused weight transpose: 5 weights f32 (RxC) -> bf16 (CxR), one dispatch.
// perm=1 (wff1): output rows interleave a/g columns: rout = 2c | 2(c-half)+1
// ---------------------------------------------------------------------------
struct TD { const float* src; bf16* dst; int R, C, base, perm; };
struct TDs5 { TD d[5]; };

__global__ __launch_bounds__(256) void wtrans_kernel(TDs5 a)
{
  const int blk = blockIdx.x;
  int di = 0;
  #pragma unroll
  for (int k = 1; k < 5; ++k) if (blk >= a.d[k].base) di = k;
  const TD d = a.d[di];
  const int local = blk - d.base;
  const int tilesX = d.C >> 5;
  const int by = local / tilesX, bx = local - by*tilesX;
  __shared__ float t[32][33];
  const int tx = threadIdx.x & 31, ty = threadIdx.x >> 5;
  const int c0 = bx*32, r0 = by*32;
  #pragma unroll
  for (int i = 0; i < 4; ++i)
    t[ty + i*8][tx] = d.src[(size_t)(r0 + ty + i*8)*d.C + c0 + tx];
  __syncthreads();
  const int half = d.C >> 1;
  #pragma unroll
  for (int i = 0; i < 4; ++i) {
    int c = c0 + ty + i*8;
    int rout = d.perm ? ((c < half) ? 2*c : 2*(c - half) + 1) : c;
    d.dst[(size_t)rout*d.R + r0 + tx] = __float2bfloat16(t[tx][ty + i*8]);
  }
}

// ---------------------------------------------------------------------------
extern "C" void kernel_launch(void* const* d_in, const int* in_sizes, int n_in,
                              void* d_out, int out_size, void* d_ws, size_t ws_size,
                              hipStream_t stream)
{
  const float* x_in       = (const float*)d_in[0];
  const float* attn_gamma = (const float*)d_in[1];
  const float* wq         = (const float*)d_in[2];
  const float* wkv        = (const float*)d_in[3];
  const float* q_scale    = (const float*)d_in[4];
  const float* k_scale    = (const float*)d_in[5];
  const float* wo         = (const float*)d_in[6];
  const float* ff_gamma   = (const float*)d_in[7];
  const float* ff_beta    = (const float*)d_in[8];
  const float* wff1       = (const float*)d_in[9];
  const float* wff2       = (const float*)d_in[10];
  float* outp = (float*)d_out;
  char* ws = (char*)d_ws;

  const size_t E = (size_t)ROWS * DIM;      // 3,145,728 elems
  // Arena (byte offsets; total 77,070,336 B — same footprint as round 4):
  float* xw32 = (float*)ws;                     // [0, 12.58M) f32 residual
  bf16*  xw16 = (bf16*)(ws + 12582912);         // [.., 18.87M) bf16 shadow
  bf16*  S_h  = (bf16*)(ws + 18874368);         // [.., 25.17M) LN out / attn out
  char*  BIGb = ws + 25165824;                  // [.., 62.91M) 37.75M scratch
  bf16*  WT   = (bf16*)(ws + 62914560);         // [.., 77.07M) transposed wts
  bf16*  qbuf  = (bf16*)BIGb;                   // E elems
  bf16*  kvbuf = qbuf + E;                      // 2E
  bf16*  qhb   = qbuf + 3*E;                    // E
  bf16*  khb   = qbuf + 4*E;                    // E
  bf16*  vtb   = qbuf + 5*E;                    // E
  bf16*  glbuf = (bf16*)BIGb;                   // ROWS*FFI (q..kh dead by then)
  float* wP    = (float*)BIGb;                  // wo partials 2*E f32 (overlays
                                                //   dead q/kv/qh regions)
  float* fP    = (float*)(BIGb + 16777216);     // ff2 partials 2*E f32 (after
                                                //   glbuf; tail spills into dead
                                                //   wqT/wkvT/woT — rebuilt next
                                                //   layer by wtrans)
  bf16*  wqT   = WT;                            // [768][768]
  bf16*  wkvT  = WT + 589824;                   // [1536][768]
  bf16*  woT   = WT + 1769472;                  // [768][768]
  bf16*  wff1T = WT + 2359296;                  // [4096][768] (interleaved a/g)
  bf16*  wff2T = WT + 5505024;                  // [768][2048]

  cast_kernel<<<1536, 256, 0, stream>>>(x_in, xw16);
  ln_kernel<<<ROWS, 256, 0, stream>>>(x_in, attn_gamma, nullptr, S_h);

  for (int i = 0; i < NDEPTH; ++i) {
    const float* xsrc = (i == 0) ? x_in : xw32;

    TDs5 td;
    td.d[0] = { wq   + (size_t)i*589824,  wqT,   768,  768,    0, 0 };
    td.d[1] = { wkv  + (size_t)i*1179648, wkvT,  768, 1536,  576, 0 };
    td.d[2] = { wo   + (size_t)i*589824,  woT,   768,  768, 1728, 0 };
    td.d[3] = { wff1 + (size_t)i*3145728, wff1T, 768, 4096, 2304, 1 };
    td.d[4] = { wff2 + (size_t)i*1572864, wff2T, 2048, 768, 5376, 0 };
    wtrans_kernel<<<6912, 256, 0, stream>>>(td);

    // q = LN_attn(x) @ wq ; kv = x @ wkv  (one dispatch; S_h holds attn-LN)
    qkv_kernel<<<dim3(12,32,2), 256, 0, stream>>>(S_h, xw16, wqT, wkvT, qbuf, kvbuf);
    // rope(q,k)+l2norm+scale (8 folded into q) ; v -> (b,h,dh,n)
    rope_kernel<<<ROWS, 384, 0, stream>>>(qbuf, kvbuf, q_scale + i*DH, k_scale + i*DH, qhb, khb);
    vtrans_kernel<<<dim3(16,48), 256, 0, stream>>>(kvbuf, vtb);
    attn_kernel<<<dim3(16,48), 256, 0, stream>>>(qhb, khb, vtb,
                                                 q_scale + i*DH, k_scale + i*DH, S_h);
    // x = x + o @ wo  (split-K=2) ; fused reduce + residual + ff-LN
    gemm_splitk_kernel<64><<<dim3(12,32,2), 256, 0, stream>>>(S_h, woT, wP, ROWS, DIM, INNER);
    redln_kernel<<<ROWS, 256, 0, stream>>>(wP, wP + E, xsrc, xw32, nullptr, nullptr,
                                           ff_gamma + i*DIM, ff_beta + i*DIM, S_h);
    // gl = a*gelu(g) fused in FF1 epilogue
    gemm_kernel<128,true><<<dim3(32,32), 256, 0, stream>>>(S_h, wff1T, glbuf, nullptr, nullptr, ROWS, 2*FFI, DIM);
    // x = x + gl @ wff2 (split-K=2) ; fused reduce + residual (+ next attn-LN)
    gemm_splitk_kernel<64><<<dim3(12,32,2), 256, 0, stream>>>(glbuf, wff2T, fP, ROWS, DIM, FFI);
    if (i < NDEPTH-1)
      redln_kernel<<<ROWS, 256, 0, stream>>>(fP, fP + E, xw32, xw32, xw16, nullptr,
                                             attn_gamma + (i+1)*DIM, nullptr, S_h);
    else
      redln_kernel<<<ROWS, 256, 0, stream>>>(fP, fP + E, xw32, nullptr, nullptr, outp,
                                             nullptr, nullptr, nullptr);
  }
}

// Round 6
// 922.271 us; speedup vs baseline: 1.8933x; 1.0962x over previous
//
#include <hip/hip_runtime.h>
#include <hip/hip_bf16.h>
#include <math.h>

typedef __hip_bfloat16 bf16;
typedef __bf16 bf16x8 __attribute__((ext_vector_type(8)));
typedef float f32x4 __attribute__((ext_vector_type(4)));

#define NDEPTH 4
#define DIM 768
#define HEADS 12
#define DH 64
#define INNER 768
#define FFI 2048
#define BB 4
#define NN 1024
#define ROWS (BB*NN)   // 4096

__device__ __forceinline__ void async_cp16(const bf16* g, bf16* l) {
  __builtin_amdgcn_global_load_lds(
      (const __attribute__((address_space(1))) unsigned int*)g,
      (__attribute__((address_space(3))) unsigned int*)l, 16, 0, 0);
}

// ---------------------------------------------------------------------------
// bf16 MFMA GEMM body. C[MxN] = A[MxK] @ Bt[NxK]^T. K, LD compile-time ->
// K-loop fully unrolled; staging addresses loop-invariant (kk folds into the
// global-load immediate offset). 128xBN tile, BK=64, 4 waves, XOR-swizzled
// LDS (conflict-free b128 reads).
// GELU: N interleaved (a,g); writes a*gelu(g) to Cb with N/2 cols.
// VOUT: cols >= INNER are V: written transposed to Vt (b,h,dh,n) packed 8B;
//       cols < INNER are K: written to Cb with stride INNER.
// ---------------------------------------------------------------------------
template<int BN, bool GELU, bool VOUT, int K, int LD>
__device__ __forceinline__ void gemm_body(
    const bf16* __restrict__ A, const bf16* __restrict__ Bt,
    bf16* __restrict__ Cb, float* __restrict__ Cf, const float* __restrict__ Rf,
    bf16* __restrict__ Vt, int M, int N, int bx, int by, bf16* As, bf16* Bs)
{
  constexpr int WN = BN / 2;      // wave col extent
  constexpr int NT = WN / 16;     // col MFMA tiles per wave
  const int tid  = threadIdx.x;
  const int lane = tid & 63, w = tid >> 6;
  const int quad = lane >> 4, l16 = lane & 15;
  const int wr = w >> 1, wc = w & 1;
  const int m0 = by * 128, n0 = bx * BN;

  f32x4 acc[4][NT] = {};

  constexpr int CHA = 128 * 8;    // A chunks (8 x 16B per 64-elem row)
  constexpr int CH  = CHA + BN * 8;
  constexpr int NCH = CH / 256;   // chunks per thread

  #pragma unroll
  for (int kk = 0; kk < K; kk += 64) {
    __syncthreads();
    #pragma unroll
    for (int t = 0; t < NCH; ++t) {
      int c0 = w*64 + t*256;      // wave-uniform LDS base chunk
      int ch = c0 + lane;
      if (c0 < CHA) {
        int r = ch >> 3, j = (ch & 7) ^ (r & 7);
        async_cp16(&A[(size_t)(m0 + r)*LD + kk + j*8], &As[(size_t)c0*8]);
      } else {
        int ch2 = ch - CHA, r = ch2 >> 3, j = (ch2 & 7) ^ (r & 7);
        async_cp16(&Bt[(size_t)(n0 + r)*LD + kk + j*8], &Bs[(size_t)(c0 - CHA)*8]);
      }
    }
    __syncthreads();   // drains vmcnt before ds_read

    #pragma unroll
    for (int kc = 0; kc < 2; ++kc) {
      bf16x8 bfr[NT];
      #pragma unroll
      for (int nt = 0; nt < NT; ++nt) {
        int rb = wc*WN + nt*16 + l16;
        int c  = (kc*4 + quad) ^ (rb & 7);
        bfr[nt] = *(const bf16x8*)&Bs[rb*64 + c*8];
      }
      #pragma unroll
      for (int mt = 0; mt < 4; ++mt) {
        int ra = wr*64 + mt*16 + l16;
        int ca = (kc*4 + quad) ^ (ra & 7);
        bf16x8 af = *(const bf16x8*)&As[ra*64 + ca*8];
        #pragma unroll
        for (int nt = 0; nt < NT; ++nt)
          acc[mt][nt] = __builtin_amdgcn_mfma_f32_16x16x32_bf16(af, bfr[nt], acc[mt][nt], 0, 0, 0);
      }
    }
  }

  #pragma unroll
  for (int mt = 0; mt < 4; ++mt) {
    #pragma unroll
    for (int nt = 0; nt < NT; ++nt) {
      int row = m0 + wr*64 + mt*16 + quad*4;
      int col = n0 + wc*WN + nt*16 + l16;
      if (GELU) {
        #pragma unroll
        for (int r = 0; r < 4; ++r) {
          float v = acc[mt][nt][r];
          float g = __shfl_xor(v, 1);            // even lane: v=a, g from odd
          if (!(lane & 1)) {
            float ge = 0.5f * g * (1.f + erff(g * 0.70710678118654752f));
            Cb[(size_t)(row + r)*(N >> 1) + (col >> 1)] = __float2bfloat16(v * ge);
          }
        }
      } else if (VOUT) {
        if (col < INNER) {                       // K half (wave-uniform branch)
          #pragma unroll
          for (int r = 0; r < 4; ++r)
            Cb[(size_t)(row + r)*INNER + col] = __float2bfloat16(acc[mt][nt][r]);
        } else {                                 // V half -> (b,h,dh,n) packed
          int c2 = col - INNER, hh = c2 >> 6, d = c2 & 63;
          int b = row >> 10, nn = row & 1023;
          union { ushort4 u4; bf16 h4[4]; } p;
          #pragma unroll
          for (int r = 0; r < 4; ++r) p.h4[r] = __float2bfloat16(acc[mt][nt][r]);
          *(ushort4*)&Vt[(((size_t)b*HEADS + hh)*DH + d)*NN + nn] = p.u4;
        }
      } else {
        #pragma unroll
        for (int r = 0; r < 4; ++r) {
          float v = acc[mt][nt][r];
          size_t idx = (size_t)(row + r) * N + col;
          if (Rf) v += Rf[idx];
          if (Cf) Cf[idx] = v;
          if (Cb) Cb[idx] = __float2bfloat16(v);
        }
      }
    }
  }
}

template<int BN, bool GELU, int K, int LD>
__global__ __launch_bounds__(256) void gemm_kernel(
    const bf16* __restrict__ A, const bf16* __restrict__ Bt,
    bf16* __restrict__ Cb, float* __restrict__ Cf, const float* __restrict__ Rf,
    int M, int N)
{
  __shared__ __align__(16) bf16 As[128*64];
  __shared__ __align__(16) bf16 Bs[BN*64];
  gemm_body<BN,GELU,false,K,LD>(A, Bt, Cb, Cf, Rf, nullptr, M, N,
                                blockIdx.x, blockIdx.y, As, Bs);
}

// Split-K=2: z selects K-half; partials to P[z*M*N]
template<int BN, int KH, int LD>
__global__ __launch_bounds__(256) void gemm_splitk_kernel(
    const bf16* __restrict__ A, const bf16* __restrict__ Bt,
    float* __restrict__ P, int M, int N)
{
  __shared__ __align__(16) bf16 As[128*64];
  __shared__ __align__(16) bf16 Bs[BN*64];
  const int z = blockIdx.z;
  gemm_body<BN,false,false,KH,LD>(A + (size_t)z*KH, Bt + (size_t)z*KH, nullptr,
                                  P + (size_t)z*M*N, nullptr, nullptr,
                                  M, N, blockIdx.x, blockIdx.y, As, Bs);
}

// q = h @ wq (BN=64); kv = x @ wkv (BN=128, k compact + v transposed) fused
__global__ __launch_bounds__(256) void qkv_kernel(
    const bf16* __restrict__ h, const bf16* __restrict__ x16,
    const bf16* __restrict__ wqT, const bf16* __restrict__ wkvT,
    bf16* __restrict__ qb, bf16* __restrict__ kb, bf16* __restrict__ vt)
{
  __shared__ __align__(16) bf16 As[128*64];
  __shared__ __align__(16) bf16 Bs[128*64];
  if (blockIdx.z == 0)
    gemm_body<64,false,false,768,768>(h, wqT, qb, nullptr, nullptr, nullptr,
                                      ROWS, INNER, blockIdx.x, blockIdx.y, As, Bs);
  else
    gemm_body<128,false,true,768,768>(x16, wkvT, kb, nullptr, nullptr, vt,
                                      ROWS, 2*INNER, blockIdx.x, blockIdx.y, As, Bs);
}

// ---------------------------------------------------------------------------
// LayerNorm (row = 768, f32 in, bf16 out) — used once for layer-0 attn-LN
// ---------------------------------------------------------------------------
__global__ __launch_bounds__(256) void ln_kernel(
    const float* __restrict__ x, const float* __restrict__ g,
    const float* __restrict__ bta, bf16* __restrict__ out)
{
  const int row = blockIdx.x, tid = threadIdx.x;
  const size_t base = (size_t)row * DIM;
  float v[3];
  #pragma unroll
  for (int j = 0; j < 3; ++j) v[j] = x[base + tid + j*256];
  float s  = v[0] + v[1] + v[2];
  float ss = v[0]*v[0] + v[1]*v[1] + v[2]*v[2];
  #pragma unroll
  for (int off = 32; off; off >>= 1) { s += __shfl_xor(s, off); ss += __shfl_xor(ss, off); }
  __shared__ float red[8];
  int w = tid >> 6;
  if ((tid & 63) == 0) { red[w] = s; red[w + 4] = ss; }
  __syncthreads();
  s  = red[0] + red[1] + red[2] + red[3];
  ss = red[4] + red[5] + red[6] + red[7];
  float mean = s * (1.f/768.f);
  float var  = ss * (1.f/768.f) - mean*mean;
  float rstd = rsqrtf(fmaxf(var, 0.f) + 1e-5f);
  #pragma unroll
  for (int j = 0; j < 3; ++j) {
    int c = tid + j*256;
    float bv = bta ? bta[c] : 0.f;
    out[base + c] = __float2bfloat16((v[j] - mean) * rstd * g[c] + bv);
  }
}

// ---------------------------------------------------------------------------
// Split-K reduce + residual + optional LN (fused). Row = 768.
// ---------------------------------------------------------------------------
__global__ __launch_bounds__(256) void redln_kernel(
    const float* __restrict__ P0, const float* __restrict__ P1,
    const float* __restrict__ res,
    float* __restrict__ xo32, bf16* __restrict__ xo16, float* __restrict__ outf,
    const float* __restrict__ g, const float* __restrict__ bta,
    bf16* __restrict__ lnout)
{
  const int row = blockIdx.x, tid = threadIdx.x;
  const size_t base = (size_t)row * DIM;
  float v[3];
  #pragma unroll
  for (int j = 0; j < 3; ++j) {
    size_t idx = base + tid + j*256;
    v[j] = res[idx] + P0[idx] + P1[idx];
    if (xo32) xo32[idx] = v[j];
    if (xo16) xo16[idx] = __float2bfloat16(v[j]);
    if (outf) outf[idx] = v[j];
  }
  if (!g) return;
  float s  = v[0] + v[1] + v[2];
  float ss = v[0]*v[0] + v[1]*v[1] + v[2]*v[2];
  #pragma unroll
  for (int off = 32; off; off >>= 1) { s += __shfl_xor(s, off); ss += __shfl_xor(ss, off); }
  __shared__ float red[8];
  int w = tid >> 6;
  if ((tid & 63) == 0) { red[w] = s; red[w + 4] = ss; }
  __syncthreads();
  s  = red[0] + red[1] + red[2] + red[3];
  ss = red[4] + red[5] + red[6] + red[7];
  float mean = s * (1.f/768.f);
  float var  = ss * (1.f/768.f) - mean*mean;
  float rstd = rsqrtf(fmaxf(var, 0.f) + 1e-5f);
  #pragma unroll
  for (int j = 0; j < 3; ++j) {
    int c = tid + j*256;
    float bv = bta ? bta[c] : 0.f;
    lnout[base + c] = __float2bfloat16((v[j] - mean) * rstd * g[c] + bv);
  }
}

// ---------------------------------------------------------------------------
// RoPE (2D, H=32) + L2-norm + per-dim scale; q gets ATTN_SCALE folded in.
// Pair-per-lane; block = 384 threads (12 heads x 32 pairs). -> (b,h,n,dh)
// ---------------------------------------------------------------------------
__global__ __launch_bounds__(384) void rope_kernel(
    const bf16* __restrict__ q, const bf16* __restrict__ kb,
    const float* __restrict__ qsc, const float* __restrict__ ksc,
    bf16* __restrict__ qh, bf16* __restrict__ kh)
{
  const int bn = blockIdx.x;
  const int b = bn >> 10, n = bn & 1023;
  const int tid = threadIdx.x;
  const int h = tid >> 5, pr = tid & 31, d0 = pr*2;
  const float xp = (float)(n & 31), yp = (float)(n >> 5);
  const int t = pr >> 1;
  const float freq = powf(10000.f, -(float)t / 16.f);
  const float ang = (pr & 1) ? yp * freq : xp * freq;
  float sn, cs;
  sincosf(ang, &sn, &cs);
  const float2 qs2 = *(const float2*)&qsc[d0];
  const float2 ks2 = *(const float2*)&ksc[d0];

  union { unsigned int u; bf16 h2[2]; } qa, ka, qo, ko;
  qa.u = *(const unsigned int*)&q [(size_t)bn*INNER + h*64 + d0];
  ka.u = *(const unsigned int*)&kb[(size_t)bn*INNER + h*64 + d0];
  float qre = __bfloat162float(qa.h2[0]), qim = __bfloat162float(qa.h2[1]);
  float kre = __bfloat162float(ka.h2[0]), kim = __bfloat162float(ka.h2[1]);
  float qr = qre*cs - qim*sn, qi = qre*sn + qim*cs;
  float kr = kre*cs - kim*sn, ki = kre*sn + kim*cs;
  float q2 = qr*qr + qi*qi, k2 = kr*kr + ki*ki;
  #pragma unroll
  for (int off = 1; off < 32; off <<= 1) { q2 += __shfl_xor(q2, off); k2 += __shfl_xor(k2, off); }
  float qinv = 8.f / fmaxf(sqrtf(q2), 1e-12f);   // ATTN_SCALE folded into q
  float kinv = 1.f / fmaxf(sqrtf(k2), 1e-12f);
  qo.h2[0] = __float2bfloat16(qr * qinv * qs2.x);
  qo.h2[1] = __float2bfloat16(qi * qinv * qs2.y);
  ko.h2[0] = __float2bfloat16(kr * kinv * ks2.x);
  ko.h2[1] = __float2bfloat16(ki * kinv * ks2.y);
  size_t oi = (((size_t)b*HEADS + h)*NN + n)*DH + d0;
  *(unsigned int*)&qh[oi] = qo.u;
  *(unsigned int*)&kh[oi] = ko.u;
}

// ---------------------------------------------------------------------------
// Flash attention, fixed softmax max (Cauchy-Schwarz bound; 8 folded into q).
// ---------------------------------------------------------------------------
__global__ __launch_bounds__(256) void attn_kernel(
    const bf16* __restrict__ qh, const bf16* __restrict__ kh,
    const bf16* __restrict__ vt, const float* __restrict__ qsc,
    const float* __restrict__ ksc, bf16* __restrict__ ob)
{
  __shared__ __align__(16) bf16 Qs[64*72];
  __shared__ __align__(16) bf16 Ks[64*72];
  __shared__ __align__(16) bf16 Vt[64*72];
  __shared__ __align__(16) bf16 Ps[4][16*72];

  const int tid = threadIdx.x;
  const int lane = tid & 63, w = tid >> 6;
  const int quad = lane >> 4, l16 = lane & 15;
  const int qt = blockIdx.x, bh = blockIdx.y;
  const int b = bh / HEADS, h = bh % HEADS;
  const size_t base = (size_t)bh * NN * DH;

  float mq = fabsf(qsc[lane]), mk = fabsf(ksc[lane]);
  #pragma unroll
  for (int off = 1; off < 64; off <<= 1) {
    mq = fmaxf(mq, __shfl_xor(mq, off));
    mk = fmaxf(mk, __shfl_xor(mk, off));
  }
  const float Mb = 8.f * mq * mk;

  for (int c = tid; c < 512; c += 256) {
    int r = c >> 3, j = c & 7;
    *(uint4*)&Qs[r*72 + j*8] = *(const uint4*)&qh[base + (size_t)(qt*64 + r)*64 + j*8];
  }

  f32x4 o[4] = {};
  float pl[4] = {0.f, 0.f, 0.f, 0.f};

  for (int kt0 = 0; kt0 < NN/64; ++kt0) {
    __syncthreads();
    for (int c = tid; c < 512; c += 256) {
      int r = c >> 3, j = c & 7;
      *(uint4*)&Ks[r*72 + j*8] = *(const uint4*)&kh[base + (size_t)(kt0*64 + r)*64 + j*8];
      *(uint4*)&Vt[r*72 + j*8] = *(const uint4*)&vt[base + (size_t)r*NN + kt0*64 + j*8];
    }
    __syncthreads();

    f32x4 s[4] = {};
    bf16x8 aq[2];
    #pragma unroll
    for (int kc = 0; kc < 2; ++kc)
      aq[kc] = *(const bf16x8*)&Qs[(w*16 + l16)*72 + kc*32 + quad*8];
    #pragma unroll
    for (int kt = 0; kt < 4; ++kt)
      #pragma unroll
      for (int kc = 0; kc < 2; ++kc) {
        bf16x8 bk = *(const bf16x8*)&Ks[(kt*16 + l16)*72 + kc*32 + quad*8];
        s[kt] = __builtin_amdgcn_mfma_f32_16x16x32_bf16(aq[kc], bk, s[kt], 0, 0, 0);
      }

    #pragma unroll
    for (int r = 0; r < 4; ++r) {
      #pragma unroll
      for (int kt = 0; kt < 4; ++kt) {
        float pv = __expf(s[kt][r] - Mb);
        pl[r] += pv;
        Ps[w][(quad*4 + r)*72 + kt*16 + l16] = __float2bfloat16(pv);
      }
    }
    __syncthreads();

    #pragma unroll
    for (int kc = 0; kc < 2; ++kc) {
      bf16x8 ap = *(const bf16x8*)&Ps[w][l16*72 + kc*32 + quad*8];
      #pragma unroll
      for (int nt = 0; nt < 4; ++nt) {
        bf16x8 bv = *(const bf16x8*)&Vt[(nt*16 + l16)*72 + kc*32 + quad*8];
        o[nt] = __builtin_amdgcn_mfma_f32_16x16x32_bf16(ap, bv, o[nt], 0, 0, 0);
      }
    }
  }

  float l[4];
  #pragma unroll
  for (int r = 0; r < 4; ++r) {
    float rs = pl[r];
    #pragma unroll
    for (int off = 1; off < 16; off <<= 1) rs += __shfl_xor(rs, off);
    l[r] = rs;
  }

  #pragma unroll
  for (int nt = 0; nt < 4; ++nt)
    #pragma unroll
    for (int r = 0; r < 4; ++r) {
      int n = qt*64 + w*16 + quad*4 + r;
      int dcol = nt*16 + l16;
      ob[((size_t)(b*NN + n)*HEADS + h)*DH + dcol] = __float2bfloat16(o[nt][r] / l[r]);
    }
}

// ---------------------------------------------------------------------------
// f32 -> bf16 cast (vectorized x8)
// ---------------------------------------------------------------------------
__global__ __launch_bounds__(256) void cast_kernel(
    const float* __restrict__ x, bf16* __restrict__ o)
{
  size_t i = ((size_t)blockIdx.x*256 + threadIdx.x) * 8;
  float4 f0 = *(const float4*)(x + i);
  float4 f1 = *(const float4*)(x + i + 4);
  union { uint4 u; bf16 h[8]; } p;
  p.h[0] = __float2bfloat16(f0.x); p.h[1] = __float2bfloat16(f0.y);
  p.h[2] = __float2bfloat16(f0.z); p.h[3] = __float2bfloat16(f0.w);
  p.h[4] = __float2bfloat16(f1.x); p.h[5] = __float2bfloat16(f1.y);
  p.h[6] = __float2bfloat16(f1.z); p.h[7] = __float2bfloat16(f1.w);
  *(uint4*)(o + i) = p.u;
}

// ---------------------------------------------------------------------------
// Fused weight transpose: 5 weights f32 (RxC) -> bf16 (CxR), one dispatch.
// perm=1 (wff1): output rows interleave a/g columns.
// ---------------------------------------------------------------------------
struct TD { const float* src; bf16* dst; int R, C, base, perm; };
struct TDs5 { TD d[5]; };

__global__ __launch_bounds__(256) void wtrans_kernel(TDs5 a)
{
  const int blk = blockIdx.x;
  int di = 0;
  #pragma unroll
  for (int k = 1; k < 5; ++k) if (blk >= a.d[k].base) di = k;
  const TD d = a.d[di];
  const int local = blk - d.base;
  const int tilesX = d.C >> 5;
  const int by = local / tilesX, bx = local - by*tilesX;
  __shared__ float t[32][33];
  const int tx = threadIdx.x & 31, ty = threadIdx.x >> 5;
  const int c0 = bx*32, r0 = by*32;
  #pragma unroll
  for (int i = 0; i < 4; ++i)
    t[ty + i*8][tx] = d.src[(size_t)(r0 + ty + i*8)*d.C + c0 + tx];
  __syncthreads();
  const int half = d.C >> 1;
  #pragma unroll
  for (int i = 0; i < 4; ++i) {
    int c = c0 + ty + i*8;
    int rout = d.perm ? ((c < half) ? 2*c : 2*(c - half) + 1) : c;
    d.dst[(size_t)rout*d.R + r0 + tx] = __float2bfloat16(t[tx][ty + i*8]);
  }
}

// ---------------------------------------------------------------------------
extern "C" void kernel_launch(void* const* d_in, const int* in_sizes, int n_in,
                              void* d_out, int out_size, void* d_ws, size_t ws_size,
                              hipStream_t stream)
{
  const float* x_in       = (const float*)d_in[0];
  const float* attn_gamma = (const float*)d_in[1];
  const float* wq         = (const float*)d_in[2];
  const float* wkv        = (const float*)d_in[3];
  const float* q_scale    = (const float*)d_in[4];
  const float* k_scale    = (const float*)d_in[5];
  const float* wo         = (const float*)d_in[6];
  const float* ff_gamma   = (const float*)d_in[7];
  const float* ff_beta    = (const float*)d_in[8];
  const float* wff1       = (const float*)d_in[9];
  const float* wff2       = (const float*)d_in[10];
  float* outp = (float*)d_out;
  char* ws = (char*)d_ws;

  const size_t E = (size_t)ROWS * DIM;      // 3,145,728 elems
  float* xw32 = (float*)ws;                     // [0, 12.58M) f32 residual
  bf16*  xw16 = (bf16*)(ws + 12582912);         // bf16 shadow (kv input)
  bf16*  S_h  = (bf16*)(ws + 18874368);         // LN out / attn out
  char*  BIGb = ws + 25165824;                  // 37.75M scratch
  bf16*  WT   = (bf16*)(ws + 62914560);         // transposed weights
  bf16*  qbuf  = (bf16*)BIGb;                   // E elems
  bf16*  kbuf  = qbuf + E;                      // E
  bf16*  qhb   = qbuf + 2*E;                    // E
  bf16*  khb   = qbuf + 3*E;                    // E
  bf16*  vtb   = qbuf + 4*E;                    // E
  bf16*  glbuf = (bf16*)BIGb;                   // ROWS*FFI (q..vt dead by then)
  float* wP    = (float*)BIGb;                  // wo partials 2E f32
  float* fP    = (float*)(BIGb + 16777216);     // ff2 partials 2E f32 (tail
                                                //   spills into dead wqT..woT,
                                                //   rebuilt next layer)
  bf16*  wqT   = WT;                            // [768][768]
  bf16*  wkvT  = WT + 589824;                   // [1536][768]
  bf16*  woT   = WT + 1769472;                  // [768][768]
  bf16*  wff1T = WT + 2359296;                  // [4096][768] (interleaved a/g)
  bf16*  wff2T = WT + 5505024;                  // [768][2048]

  cast_kernel<<<1536, 256, 0, stream>>>(x_in, xw16);
  ln_kernel<<<ROWS, 256, 0, stream>>>(x_in, attn_gamma, nullptr, S_h);

  for (int i = 0; i < NDEPTH; ++i) {
    const float* xsrc = (i == 0) ? x_in : xw32;

    TDs5 td;
    td.d[0] = { wq   + (size_t)i*589824,  wqT,   768,  768,    0, 0 };
    td.d[1] = { wkv  + (size_t)i*1179648, wkvT,  768, 1536,  576, 0 };
    td.d[2] = { wo   + (size_t)i*589824,  woT,   768,  768, 1728, 0 };
    td.d[3] = { wff1 + (size_t)i*3145728, wff1T, 768, 4096, 2304, 1 };
    td.d[4] = { wff2 + (size_t)i*1572864, wff2T, 2048, 768, 5376, 0 };
    wtrans_kernel<<<6912, 256, 0, stream>>>(td);

    // q = LN_attn(x) @ wq ; k,v = x @ wkv (k compact, v transposed in-epilogue)
    qkv_kernel<<<dim3(12,32,2), 256, 0, stream>>>(S_h, xw16, wqT, wkvT, qbuf, kbuf, vtb);
    // rope(q,k) + l2norm + scale (8 folded into q)
    rope_kernel<<<ROWS, 384, 0, stream>>>(qbuf, kbuf, q_scale + i*DH, k_scale + i*DH, qhb, khb);
    attn_kernel<<<dim3(16,48), 256, 0, stream>>>(qhb, khb, vtb,
                                                 q_scale + i*DH, k_scale + i*DH, S_h);
    // x = x + o @ wo (split-K=2) ; fused reduce + residual + ff-LN
    gemm_splitk_kernel<64,384,768><<<dim3(12,32,2), 256, 0, stream>>>(S_h, woT, wP, ROWS, DIM);
    redln_kernel<<<ROWS, 256, 0, stream>>>(wP, wP + E, xsrc, xw32, nullptr, nullptr,
                                           ff_gamma + i*DIM, ff_beta + i*DIM, S_h);
    // gl = a*gelu(g) fused in FF1 epilogue
    gemm_kernel<128,true,768,768><<<dim3(32,32), 256, 0, stream>>>(S_h, wff1T, glbuf, nullptr, nullptr, ROWS, 2*FFI);
    // x = x + gl @ wff2 (split-K=2) ; fused reduce + residual (+ next attn-LN)
    gemm_splitk_kernel<64,1024,2048><<<dim3(12,32,2), 256, 0, stream>>>(glbuf, wff2T, fP, ROWS, DIM);
    if (i < NDEPTH-1)
      redln_kernel<<<ROWS, 256, 0, stream>>>(fP, fP + E, xw32, xw32, xw16, nullptr,
                                             attn_gamma + (i+1)*DIM, nullptr, S_h);
    else
      redln_kernel<<<ROWS, 256, 0, stream>>>(fP, fP + E, xw32, nullptr, nullptr, outp,
                                             nullptr, nullptr, nullptr);
  }
}